// Round 10
// baseline (633.066 us; speedup 1.0000x reference)
//
#include <hip/hip_runtime.h>
#include <math.h>

#define Bn 256
#define Tn 256

__constant__ int EB[32] = {0,3,5,8,10,13,15,18,22,25,29,33,38,42,48,53,59,66,73,80,89,97,107,117,128,140,153,167,183,199,216,256};

__device__ __forceinline__ float fsig(float x){ return __builtin_amdgcn_rcpf(1.f + __expf(-x)); }
__device__ __forceinline__ float ftanh(float x){ return 1.f - 2.f*__builtin_amdgcn_rcpf(1.f + __expf(2.f*x)); }

__device__ __forceinline__ void gload16(const float* g, float* l){
  __builtin_amdgcn_global_load_lds((const __attribute__((address_space(1))) void*)g,
                                   (__attribute__((address_space(3))) void*)l, 16, 0, 0);
}

#define KEEP(x) asm volatile("" : "+v"(x))

typedef float v2f __attribute__((ext_vector_type(2)));

#define DOT16(res, X, W) do{ float _s0=0.f,_s1=0.f,_s2=0.f,_s3=0.f; \
  _Pragma("unroll") for (int _e=0;_e<4;++_e){ \
    _s0=fmaf((X)[_e],(W)[_e],_s0); _s1=fmaf((X)[4+_e],(W)[4+_e],_s1); \
    _s2=fmaf((X)[8+_e],(W)[8+_e],_s2); _s3=fmaf((X)[12+_e],(W)[12+_e],_s3);} \
  (res)=(_s0+_s1)+(_s2+_s3); }while(0)

#define DOT8(res, X, W) do{ float _s0=0.f,_s1=0.f; \
  _Pragma("unroll") for (int _e=0;_e<4;++_e){ \
    _s0=fmaf((X)[_e],(W)[_e],_s0); _s1=fmaf((X)[4+_e],(W)[4+_e],_s1);} \
  (res)=_s0+_s1; }while(0)

#define FMA44(A, X, W) do{ \
  (A)[0]=fmaf((X).x,(W)[0].x,(A)[0]); (A)[1]=fmaf((X).x,(W)[0].y,(A)[1]); (A)[2]=fmaf((X).x,(W)[0].z,(A)[2]); (A)[3]=fmaf((X).x,(W)[0].w,(A)[3]); \
  (A)[0]=fmaf((X).y,(W)[1].x,(A)[0]); (A)[1]=fmaf((X).y,(W)[1].y,(A)[1]); (A)[2]=fmaf((X).y,(W)[1].z,(A)[2]); (A)[3]=fmaf((X).y,(W)[1].w,(A)[3]); \
  (A)[0]=fmaf((X).z,(W)[2].x,(A)[0]); (A)[1]=fmaf((X).z,(W)[2].y,(A)[1]); (A)[2]=fmaf((X).z,(W)[2].z,(A)[2]); (A)[3]=fmaf((X).z,(W)[2].w,(A)[3]); \
  (A)[0]=fmaf((X).w,(W)[3].x,(A)[0]); (A)[1]=fmaf((X).w,(W)[3].y,(A)[1]); (A)[2]=fmaf((X).w,(W)[3].z,(A)[2]); (A)[3]=fmaf((X).w,(W)[3].w,(A)[3]); \
}while(0)

// ---------- k0: weight prep (unchanged, verified)
__global__ __launch_bounds__(256) void k0(const float* __restrict__ wfc, const float* __restrict__ bfc,
    const float* __restrict__ wih0, const float* __restrict__ bih0,
    const float* __restrict__ glw_ih, const float* __restrict__ glb_ih,
    const float* __restrict__ ghw_ih, const float* __restrict__ ghb_ih,
    float* __restrict__ wcT, float* __restrict__ bc,
    float* __restrict__ wBT, float* __restrict__ bB){
  int i = blockIdx.x*256 + threadIdx.x;
  if (i < 6144){
    int k = i/96, o = i - (i/96)*96;
    float s = 0.f;
    #pragma unroll
    for (int kk = 0; kk < 32; ++kk) s = fmaf(wih0[o*32+kk], wfc[kk*64+k], s);
    wcT[i] = s;
  } else if (i < 6240){
    int o = i - 6144;
    float s = bih0[o];
    #pragma unroll
    for (int kk = 0; kk < 32; ++kk) s = fmaf(wih0[o*32+kk], bfc[kk], s);
    bc[o] = s;
  } else if (i < 13920){
    int j = i - 6240;
    if (j < 6144){
      int og = j >> 7, rem = j & 127, k = rem >> 2, jj = rem & 3;
      int o = og*4 + jj; int g = o/96, r = o - g*96;
      wBT[j] = glw_ih[(g*96 + r)*32 + k];
    } else {
      int j2 = j - 6144;
      int oh = j2 >> 6, rem = j2 & 63, k = rem >> 2, jj = rem & 3;
      int o = oh*4 + jj; int g = o/48, r = o - g*48;
      wBT[j] = ghw_ih[(g*48 + r)*16 + k];
    }
  } else if (i < 14208){
    int o = i - 13920;
    bB[o] = (o < 192) ? glb_ih[o] : ghb_ih[o - 192];
  }
}

// ---------- kM: per-batch mega kernel. 256 blocks x 320 threads (5 waves).
// Phase A: gi0 GEMM (k1). Phase B: stage1 pipelined GRU (kS1, waves 0-1).
// Phase C: fc_in+PReLU+projections (kP). Phase D: low GRU pipeline (waves 0-3) + high GRU (wave 4).
__global__ __launch_bounds__(320,1) void kM(const float* __restrict__ mi,
    const float* __restrict__ wcT, const float* __restrict__ bc,
    const float* __restrict__ whh0, const float* __restrict__ bhh0,
    const float* __restrict__ wih1, const float* __restrict__ whh1,
    const float* __restrict__ bih1, const float* __restrict__ bhh1,
    const float* __restrict__ fco,
    const float* __restrict__ lpi,
    const float* __restrict__ wlo, const float* __restrict__ plo,
    const float* __restrict__ whi, const float* __restrict__ phi,
    const float* __restrict__ wBT, const float* __restrict__ bB,
    const float* __restrict__ wihL, const float* __restrict__ whhL,
    const float* __restrict__ bihL, const float* __restrict__ bhhL,
    const float* __restrict__ whhH, const float* __restrict__ bhhH,
    float* __restrict__ gi0w, float* __restrict__ bmA,
    float* __restrict__ giL, float* __restrict__ giH,
    float* __restrict__ acc, float* __restrict__ dfh)
{
  __shared__ __attribute__((aligned(16))) float smem[15648];
  const int tid = threadIdx.x;
  const int wid = tid >> 6;
  const int lane = tid & 63;
  const int b = blockIdx.x;

  // ================= Phase A: gi0[b][t][96] =================
  {
    float* mbuf = smem;               // 33*36 = 1188
    for (int tile = 0; tile < 8; ++tile){
      const int t0 = tile*32;
      const int bt0 = b*256 + t0;
      for (int idx = tid; idx < 264; idx += 320){
        int row = idx >> 3, c4 = idx & 7;
        int r = t0 - 1 + row;
        float4 v = make_float4(0.f,0.f,0.f,0.f);
        if (r >= 0) v = *(const float4*)&mi[(b*256 + r)*32 + c4*4];
        *(float4*)&mbuf[row*36 + c4*4] = v;
      }
      __syncthreads();
      if (tid < 256){
        const int og = tid >> 3, btg = tid & 7;
        if (og < 24){
          float a4[4][4];
          #pragma unroll
          for (int bj = 0; bj < 4; ++bj){ a4[bj][0]=0.f; a4[bj][1]=0.f; a4[bj][2]=0.f; a4[bj][3]=0.f; }
          for (int fq = 0; fq < 8; ++fq){
            float4 wvp[4], wvc[4];
            #pragma unroll
            for (int i = 0; i < 4; ++i){
              int f = fq*4 + i;
              wvp[i] = *(const float4*)&wcT[(2*f)*96 + og*4];
              wvc[i] = *(const float4*)&wcT[(2*f+1)*96 + og*4];
            }
            #pragma unroll
            for (int bj = 0; bj < 4; ++bj){
              int btl = btg + 8*bj;
              float4 xp = *(const float4*)&mbuf[btl*36 + fq*4];
              float4 xc = *(const float4*)&mbuf[(btl+1)*36 + fq*4];
              FMA44(a4[bj], xp, wvp);
              FMA44(a4[bj], xc, wvc);
            }
          }
          float4 bias = *(const float4*)&bc[og*4];
          #pragma unroll
          for (int bj = 0; bj < 4; ++bj){
            int btl = btg + 8*bj;
            float4 o;
            o.x = a4[bj][0] + bias.x; o.y = a4[bj][1] + bias.y;
            o.z = a4[bj][2] + bias.z; o.w = a4[bj][3] + bias.w;
            *(float4*)&gi0w[(bt0 + btl)*96 + og*4] = o;
          }
        }
      }
      __syncthreads();
    }
  }

  // ================= Phase B: stage1 pipelined double GRU (kS1) =================
  {
    const int q = lane >> 5, h = lane & 31, ko = q*16;
    float* y1buf = smem + 6144;       // [2][32]
    float* h1arr = smem + 6208;
    float* h2arr = smem + 6240;
    const float* gsrc = gi0w + b*24576;
    float wI[3][16], wH[3][16], wF[16];
    float b0=0.f, b1=0.f, b2=0.f, b3=0.f;
    #pragma unroll
    for (int g = 0; g < 3; ++g)
      #pragma unroll
      for (int k = 0; k < 16; ++k){ wI[g][k]=0.f; wH[g][k]=0.f; }
    #pragma unroll
    for (int k = 0; k < 16; ++k) wF[k] = 0.f;
    if (wid == 0){
      #pragma unroll
      for (int g = 0; g < 3; ++g){
        const float* w = whh0 + (g*32+h)*32 + ko;
        #pragma unroll
        for (int k = 0; k < 16; ++k){ wI[g][k] = w[k]; wH[g][k] = w[k]; }
      }
      b0 = bhh0[h]; b1 = bhh0[32+h]; b2 = bhh0[64+h];
      #pragma unroll
      for (int c0 = 0; c0 < 2; ++c0)
        for (int it = 0; it < 12; ++it)
          gload16(gsrc + c0*3072 + it*256 + lane*4, &smem[c0*3072 + it*256]);
      asm volatile("s_waitcnt vmcnt(0)" ::: "memory");
    } else if (wid == 1){
      #pragma unroll
      for (int g = 0; g < 3; ++g){
        const float* wi = wih1 + (g*32+h)*32 + ko;
        const float* wh = whh1 + (g*32+h)*32 + ko;
        #pragma unroll
        for (int k = 0; k < 16; ++k){ wI[g][k] = wi[k]; wH[g][k] = wh[k]; }
      }
      #pragma unroll
      for (int k = 0; k < 16; ++k) wF[k] = fco[(ko+k)*32 + h];
      b0 = bih1[h] + bhh1[h];
      b1 = bih1[32+h] + bhh1[32+h];
      b2 = bih1[64+h];
      b3 = bhh1[64+h];
    }
    #pragma unroll
    for (int g = 0; g < 3; ++g){
      #pragma unroll
      for (int k = 0; k < 16; ++k){ KEEP(wI[g][k]); KEEP(wH[g][k]); }
    }
    #pragma unroll
    for (int k = 0; k < 16; ++k) KEEP(wF[k]);
    __syncthreads();

    float hv[16];
    #pragma unroll
    for (int k = 0; k < 16; ++k) hv[k] = 0.f;
    float hOwn = 0.f;
    float c_r = 0.f, c_z = 0.f, c_n = 0.f, p_r = 0.f, p_z = 0.f, p_n = 0.f;

    for (int s = 0; s <= Tn; ++s){
      __syncthreads();
      if (wid == 0){
        if (s < Tn){
          const int t = s;
          if ((t & 31) == 0){
            if (t){
              int c = t >> 5;
              if (c < 7){
                for (int it = 0; it < 12; ++it)
                  gload16(gsrc + (c+1)*3072 + it*256 + lane*4, &smem[((c+1)&1)*3072 + it*256]);
              }
            }
            const float* gt = &smem[((t>>5)&1)*3072 + (t&31)*96];
            c_r = gt[h]; c_z = gt[32+h]; c_n = gt[64+h];
          } else { c_r = p_r; c_z = p_z; c_n = p_n; }
          if ((t+1) & 31){
            const float* gn = &smem[(((t+1)>>5)&1)*3072 + ((t+1)&31)*96];
            p_r = gn[h]; p_z = gn[32+h]; p_n = gn[64+h];
          }
          float pr, pz, pn;
          DOT16(pr, hv, wI[0]); DOT16(pz, hv, wI[1]); DOT16(pn, hv, wI[2]);
          pr += __shfl_xor(pr,32); pz += __shfl_xor(pz,32); pn += __shfl_xor(pn,32);
          float r = fsig(c_r + pr + b0);
          float z = fsig(c_z + pz + b1);
          float nn = ftanh(c_n + r*(pn + b2));
          float hn = nn + z*(hOwn - nn);
          hOwn = hn;
          h1arr[h] = hn;
          if (q == 0) y1buf[(s & 1)*32 + h] = hn;
          *(float4*)&hv[0]  = *(const float4*)&h1arr[ko+0];
          *(float4*)&hv[4]  = *(const float4*)&h1arr[ko+4];
          *(float4*)&hv[8]  = *(const float4*)&h1arr[ko+8];
          *(float4*)&hv[12] = *(const float4*)&h1arr[ko+12];
        }
      } else if (wid == 1){
        if (s >= 1){
          const int t = s - 1;
          const float* yb = &y1buf[(t & 1)*32];
          float xv[16];
          *(float4*)&xv[0]  = *(const float4*)&yb[ko+0];
          *(float4*)&xv[4]  = *(const float4*)&yb[ko+4];
          *(float4*)&xv[8]  = *(const float4*)&yb[ko+8];
          *(float4*)&xv[12] = *(const float4*)&yb[ko+12];
          float ur, uz, ui, vr, vz, vh;
          DOT16(ur, xv, wI[0]); DOT16(uz, xv, wI[1]); DOT16(ui, xv, wI[2]);
          DOT16(vr, hv, wH[0]); DOT16(vz, hv, wH[1]); DOT16(vh, hv, wH[2]);
          float qr = ur + vr, qz = uz + vz;
          qr += __shfl_xor(qr,32); qz += __shfl_xor(qz,32);
          ui += __shfl_xor(ui,32); vh += __shfl_xor(vh,32);
          float r1 = fsig(qr + b0);
          float z1 = fsig(qz + b1);
          float n1 = ftanh(ui + b2 + r1*(vh + b3));
          float hn = n1 + z1*(hOwn - n1);
          hOwn = hn;
          h2arr[h] = hn;
          *(float4*)&hv[0]  = *(const float4*)&h2arr[ko+0];
          *(float4*)&hv[4]  = *(const float4*)&h2arr[ko+4];
          *(float4*)&hv[8]  = *(const float4*)&h2arr[ko+8];
          *(float4*)&hv[12] = *(const float4*)&h2arr[ko+12];
          float sf = 0.f;
          #pragma unroll
          for (int k = 0; k < 16; ++k) sf = fmaf(xv[k] + hv[k], wF[k], sf);
          sf += __shfl_xor(sf,32);
          if (q == 0) bmA[(b*Tn + t)*32 + h] = fsig(sf);
        }
      }
    }
    __syncthreads();
  }

  // ================= Phase C: fc_in + PReLU + gi projections (kP) =================
  {
    float* xb = smem;                 // 32*292 = 9344
    float* mb = smem + 9344;          // 32*100 = 3200
    for (int tile = 0; tile < 8; ++tile){
      const int t0 = tile*32;
      const int bt0 = b*256 + t0;
      if (tid < 256){
        #pragma unroll
        for (int j = 0; j < 8; ++j){
          int idx = j*256 + tid;
          int row = idx >> 6, c4 = idx & 63;
          float4 v = *(const float4*)&lpi[(bt0 + row)*256 + c4*4];
          *(float4*)&xb[row*292 + c4*4] = v;
        }
        {
          int row = tid >> 3, c4 = tid & 7;
          float4 v = *(const float4*)&bmA[(bt0 + row)*32 + c4*4];
          *(float4*)&xb[row*292 + 256 + c4*4] = v;
        }
      }
      __syncthreads();
      if (tid < 256){
        const int og = tid >> 3, btg = tid & 7;
        if (og < 16){
          float a4[4][4];
          #pragma unroll
          for (int bj = 0; bj < 4; ++bj){ a4[bj][0]=0.f; a4[bj][1]=0.f; a4[bj][2]=0.f; a4[bj][3]=0.f; }
          for (int kq = 0; kq < 40; ++kq){
            int k0_ = kq*4;
            int kk = (k0_ < 128) ? k0_ : k0_ + 128;
            float4 wv[4];
            #pragma unroll
            for (int i = 0; i < 4; ++i) wv[i] = *(const float4*)&wlo[(k0_+i)*64 + og*4];
            #pragma unroll
            for (int bj = 0; bj < 4; ++bj){
              float4 xv = *(const float4*)&xb[(btg + 8*bj)*292 + kk];
              FMA44(a4[bj], xv, wv);
            }
          }
          const float a = plo[0];
          #pragma unroll
          for (int bj = 0; bj < 4; ++bj){
            float4 m;
            m.x = a4[bj][0] >= 0.f ? a4[bj][0] : a*a4[bj][0];
            m.y = a4[bj][1] >= 0.f ? a4[bj][1] : a*a4[bj][1];
            m.z = a4[bj][2] >= 0.f ? a4[bj][2] : a*a4[bj][2];
            m.w = a4[bj][3] >= 0.f ? a4[bj][3] : a*a4[bj][3];
            *(float4*)&mb[(btg + 8*bj)*100 + og*4] = m;
          }
        } else if (og < 24){
          int o0 = (og - 16)*4;
          int g = o0 >> 4, r0 = o0 & 15;
          int xoff = 128 + g*80;
          float a4[4][4];
          #pragma unroll
          for (int bj = 0; bj < 4; ++bj){ a4[bj][0]=0.f; a4[bj][1]=0.f; a4[bj][2]=0.f; a4[bj][3]=0.f; }
          for (int kq = 0; kq < 20; ++kq){
            int k0_ = kq*4;
            float4 wv[4];
            #pragma unroll
            for (int i = 0; i < 4; ++i) wv[i] = *(const float4*)&whi[(g*80 + k0_ + i)*16 + r0];
            #pragma unroll
            for (int bj = 0; bj < 4; ++bj){
              float4 xv = *(const float4*)&xb[(btg + 8*bj)*292 + xoff + k0_];
              FMA44(a4[bj], xv, wv);
            }
          }
          const float a = phi[0];
          #pragma unroll
          for (int bj = 0; bj < 4; ++bj){
            float4 m;
            m.x = a4[bj][0] >= 0.f ? a4[bj][0] : a*a4[bj][0];
            m.y = a4[bj][1] >= 0.f ? a4[bj][1] : a*a4[bj][1];
            m.z = a4[bj][2] >= 0.f ? a4[bj][2] : a*a4[bj][2];
            m.w = a4[bj][3] >= 0.f ? a4[bj][3] : a*a4[bj][3];
            *(float4*)&mb[(btg + 8*bj)*100 + 64 + o0] = m;
          }
        }
      }
      __syncthreads();
      if (tid < 256){
        const int og = tid >> 3, btg = tid & 7;
        for (int og2 = og; og2 < 72; og2 += 32){
          int woff, kbase, K, obase, dstride;
          float* dst;
          float4 bias;
          if (og2 < 48){
            woff = og2*128; kbase = (og2 >= 24) ? 32 : 0; K = 32;
            obase = og2*4; dst = giL; dstride = 192;
            bias = *(const float4*)&bB[obase];
          } else {
            int oh = og2 - 48;
            woff = 6144 + oh*64;
            int o0 = oh*4; int g = o0/48;
            kbase = 64 + g*16; K = 16;
            obase = o0; dst = giH; dstride = 96;
            bias = *(const float4*)&bB[192 + o0];
          }
          float a4[4][4];
          #pragma unroll
          for (int bj = 0; bj < 4; ++bj){ a4[bj][0]=0.f; a4[bj][1]=0.f; a4[bj][2]=0.f; a4[bj][3]=0.f; }
          for (int kq = 0; kq < K/4; ++kq){
            float4 wv[4];
            #pragma unroll
            for (int i = 0; i < 4; ++i) wv[i] = *(const float4*)&wBT[woff + (kq*4 + i)*4];
            #pragma unroll
            for (int bj = 0; bj < 4; ++bj){
              float4 xv = *(const float4*)&mb[(btg + 8*bj)*100 + kbase + kq*4];
              FMA44(a4[bj], xv, wv);
            }
          }
          #pragma unroll
          for (int bj = 0; bj < 4; ++bj){
            int btl = btg + 8*bj;
            float4 o;
            o.x = a4[bj][0] + bias.x; o.y = a4[bj][1] + bias.y;
            o.z = a4[bj][2] + bias.z; o.w = a4[bj][3] + bias.w;
            *(float4*)&dst[(bt0 + btl)*dstride + obase] = o;
          }
        }
      }
      __syncthreads();
    }
  }

  // ================= Phase D: low pipelined GRU (waves 0-3) + high GRU (wave 4) =================
  {
    const int role = wid >> 1;
    const int g = wid & 1;
    const int q = lane >> 5, h = lane & 31, ko = q*16;
    const int gH = lane >> 5, qH = (lane >> 4) & 1, hH = lane & 15, koH = qH*8;
    float* y0buf = smem + 12288;      // [2][64]
    float* h0arr = smem + 12416 + g*32;
    float* h1l   = smem + 12480;      // [2][32]
    float* gibH  = smem + 12544;      // [2][1536]
    float* harrH = smem + 15616;      // [32]
    const float* gsrcL = giL + b*49152 + g*96;
    const float* gsrcH = giH + b*24576;

    float wI[3][16], wH[3][16];
    float b0=0.f, b1=0.f, b2=0.f, b3=0.f;
    #pragma unroll
    for (int gt = 0; gt < 3; ++gt)
      #pragma unroll
      for (int k = 0; k < 16; ++k){ wI[gt][k]=0.f; wH[gt][k]=0.f; }
    if (wid < 4){
      if (role == 0){
        #pragma unroll
        for (int gt = 0; gt < 3; ++gt){
          const float* w = whhL + (g*96 + gt*32 + h)*32 + ko;
          #pragma unroll
          for (int k = 0; k < 16; ++k){ wI[gt][k] = w[k]; wH[gt][k] = w[k]; }
        }
        b0 = bhhL[g*96+h]; b1 = bhhL[g*96+32+h]; b2 = bhhL[g*96+64+h];
        #pragma unroll
        for (int c0 = 0; c0 < 2; ++c0)
          for (int it = 0; it < 12; ++it){
            int i = it*64 + lane;
            int toff = i/24, c4 = i - toff*24;
            gload16(gsrcL + (c0*32 + toff)*192 + c4*4, &smem[g*6144 + c0*3072 + it*256]);
          }
        asm volatile("s_waitcnt vmcnt(0)" ::: "memory");
      } else {
        #pragma unroll
        for (int gt = 0; gt < 3; ++gt){
          const float* wi = wihL + ((2+g)*96 + gt*32 + h)*32 + ko;
          const float* wh = whhL + ((2+g)*96 + gt*32 + h)*32 + ko;
          #pragma unroll
          for (int k = 0; k < 16; ++k){ wI[gt][k] = wi[k]; wH[gt][k] = wh[k]; }
        }
        b0 = bihL[(2+g)*96+h]    + bhhL[(2+g)*96+h];
        b1 = bihL[(2+g)*96+32+h] + bhhL[(2+g)*96+32+h];
        b2 = bihL[(2+g)*96+64+h];
        b3 = bhhL[(2+g)*96+64+h];
      }
    } else {
      #pragma unroll
      for (int gt = 0; gt < 3; ++gt){
        const float* wp = whhH + (gH*48 + gt*16 + hH)*16 + koH;
        #pragma unroll
        for (int k = 0; k < 8; ++k) wI[gt][k] = wp[k];
      }
      b0 = bhhH[gH*48+hH]; b1 = bhhH[gH*48+16+hH]; b2 = bhhH[gH*48+32+hH];
      #pragma unroll
      for (int c0 = 0; c0 < 2; ++c0)
        for (int it = 0; it < 6; ++it)
          gload16(gsrcH + c0*1536 + it*256 + lane*4, &gibH[c0*1536 + it*256]);
      asm volatile("s_waitcnt vmcnt(0)" ::: "memory");
    }
    #pragma unroll
    for (int gt = 0; gt < 3; ++gt){
      #pragma unroll
      for (int k = 0; k < 16; ++k){ KEEP(wI[gt][k]); KEEP(wH[gt][k]); }
    }
    __syncthreads();

    float hv[16];
    #pragma unroll
    for (int k = 0; k < 16; ++k) hv[k] = 0.f;
    float hOwn = 0.f;
    float c_r = 0.f, c_z = 0.f, c_n = 0.f, p_r = 0.f, p_z = 0.f, p_n = 0.f;
    const int spos = ((h&1)<<5) + (g<<4) + (h>>1);

    for (int s = 0; s <= Tn; ++s){
      __syncthreads();
      if (wid < 4){
        if (role == 0){
          if (s < Tn){
            const int t = s;
            if ((t & 31) == 0){
              if (t){
                int c = t >> 5;
                if (c < 7){
                  for (int it = 0; it < 12; ++it){
                    int i = it*64 + lane;
                    int toff = i/24, c4 = i - toff*24;
                    gload16(gsrcL + ((c+1)*32 + toff)*192 + c4*4, &smem[g*6144 + ((c+1)&1)*3072 + it*256]);
                  }
                }
              }
              const float* gt = &smem[g*6144 + ((t>>5)&1)*3072 + (t&31)*96];
              c_r = gt[h]; c_z = gt[32+h]; c_n = gt[64+h];
            } else { c_r = p_r; c_z = p_z; c_n = p_n; }
            if ((t+1) & 31){
              const float* gn = &smem[g*6144 + (((t+1)>>5)&1)*3072 + ((t+1)&31)*96];
              p_r = gn[h]; p_z = gn[32+h]; p_n = gn[64+h];
            }
            float pr, pz, pn;
            DOT16(pr, hv, wI[0]); DOT16(pz, hv, wI[1]); DOT16(pn, hv, wI[2]);
            pr += __shfl_xor(pr,32); pz += __shfl_xor(pz,32); pn += __shfl_xor(pn,32);
            float r = fsig(c_r + pr + b0);
            float z = fsig(c_z + pz + b1);
            float nn = ftanh(c_n + r*(pn + b2));
            float hn = nn + z*(hOwn - nn);
            hOwn = hn;
            h0arr[h] = hn;
            if (q == 0) y0buf[(s&1)*64 + spos] = hn;
            *(float4*)&hv[0]  = *(const float4*)&h0arr[ko+0];
            *(float4*)&hv[4]  = *(const float4*)&h0arr[ko+4];
            *(float4*)&hv[8]  = *(const float4*)&h0arr[ko+8];
            *(float4*)&hv[12] = *(const float4*)&h0arr[ko+12];
          }
        } else {
          if (s >= 1){
            const int t = s - 1;
            const float* yb = &y0buf[(t&1)*64];
            float xv[16];
            *(float4*)&xv[0]  = *(const float4*)&yb[g*32 + ko + 0];
            *(float4*)&xv[4]  = *(const float4*)&yb[g*32 + ko + 4];
            *(float4*)&xv[8]  = *(const float4*)&yb[g*32 + ko + 8];
            *(float4*)&xv[12] = *(const float4*)&yb[g*32 + ko + 12];
            float yown = yb[g*32 + h];
            float ur, uz, ui, vr, vz, vh;
            DOT16(ur, xv, wI[0]); DOT16(uz, xv, wI[1]); DOT16(ui, xv, wI[2]);
            DOT16(vr, hv, wH[0]); DOT16(vz, hv, wH[1]); DOT16(vh, hv, wH[2]);
            float qr = ur + vr, qz = uz + vz;
            qr += __shfl_xor(qr,32); qz += __shfl_xor(qz,32);
            ui += __shfl_xor(ui,32); vh += __shfl_xor(vh,32);
            float r1 = fsig(qr + b0);
            float z1 = fsig(qz + b1);
            float n1 = ftanh(ui + b2 + r1*(vh + b3));
            float hn = n1 + z1*(hOwn - n1);
            hOwn = hn;
            h1l[g*32 + h] = hn;
            *(float4*)&hv[0]  = *(const float4*)&h1l[g*32 + ko+0];
            *(float4*)&hv[4]  = *(const float4*)&h1l[g*32 + ko+4];
            *(float4*)&hv[8]  = *(const float4*)&h1l[g*32 + ko+8];
            *(float4*)&hv[12] = *(const float4*)&h1l[g*32 + ko+12];
            if (q == 0) acc[(b*256 + t)*64 + g*32 + h] = yown + hn;
          }
        }
      } else {
        if (s < Tn){
          const int t = s;
          if ((t & 15) == 0){
            if (t){
              int c = t >> 4;
              if (c < 15){
                const float* gs = gsrcH + (c+1)*1536;
                for (int it = 0; it < 6; ++it)
                  gload16(gs + it*256 + lane*4, &gibH[((c+1)&1)*1536 + it*256]);
                asm volatile("s_waitcnt vmcnt(6)" ::: "memory");
              } else {
                asm volatile("s_waitcnt vmcnt(0)" ::: "memory");
              }
            }
            const float* gt = &gibH[((t>>4)&1)*1536 + (t&15)*96 + gH*48];
            c_r = gt[hH]; c_z = gt[16+hH]; c_n = gt[32+hH];
          } else { c_r = p_r; c_z = p_z; c_n = p_n; }
          if ((t+1) & 15){
            const float* gn = &gibH[(((t+1)>>4)&1)*1536 + ((t+1)&15)*96 + gH*48];
            p_r = gn[hH]; p_z = gn[16+hH]; p_n = gn[32+hH];
          }
          float pr, pz, pn;
          DOT8(pr, hv, wI[0]); DOT8(pz, hv, wI[1]); DOT8(pn, hv, wI[2]);
          pr += __shfl_xor(pr,16); pz += __shfl_xor(pz,16); pn += __shfl_xor(pn,16);
          float r = fsig(c_r + pr + b0);
          float z = fsig(c_z + pz + b1);
          float nn = ftanh(c_n + r*(pn + b2));
          float hn = nn + z*(hOwn - nn);
          hOwn = hn;
          harrH[gH*16 + hH] = hn;
          *(float4*)&hv[0] = *(const float4*)&harrH[gH*16 + koH + 0];
          *(float4*)&hv[4] = *(const float4*)&harrH[gH*16 + koH + 4];
          if (qH == 0) dfh[(b*256 + t)*32 + gH*16 + hH] = hn;
        }
      }
    }
  }
}

// ---------- k7: register-resident masks + nontemporal stores (unchanged, verified)
__global__ __launch_bounds__(256) void k7(const float* __restrict__ acc,
    const float* __restrict__ dfh, const float* __restrict__ bmA,
    const float* __restrict__ wlo, const float* __restrict__ whi,
    const float* __restrict__ spec, float* __restrict__ out)
{
  __shared__ float accs[32][65];
  __shared__ float dfhs[32][33];
  __shared__ float bmt[32][33];
  __shared__ float frcs[257];
  __shared__ int   ibds[257];
  const int tid = threadIdx.x;
  const int b  = blockIdx.x >> 3;
  const int t0 = (blockIdx.x & 7) * 32;
  for (int idx = tid; idx < 32*16; idx += 256){
    int tl = idx >> 4, c4 = (idx & 15)*4;
    float4 v = *(const float4*)&acc[(b*256 + t0 + tl)*64 + c4];
    accs[tl][c4] = v.x; accs[tl][c4+1] = v.y; accs[tl][c4+2] = v.z; accs[tl][c4+3] = v.w;
  }
  for (int idx = tid; idx < 32*8; idx += 256){
    int tl = idx >> 3, c4 = (idx & 7)*4;
    float4 v = *(const float4*)&dfh[(b*256 + t0 + tl)*32 + c4];
    dfhs[tl][c4] = v.x; dfhs[tl][c4+1] = v.y; dfhs[tl][c4+2] = v.z; dfhs[tl][c4+3] = v.w;
    float4 u = *(const float4*)&bmA[(b*Tn + t0 + tl)*32 + c4];
    bmt[tl][c4] = u.x; bmt[tl][c4+1] = u.y; bmt[tl][c4+2] = u.z; bmt[tl][c4+3] = u.w;
  }
  for (int f = tid; f < 257; f += 256){
    int i = 0;
    #pragma unroll
    for (int k = 1; k < 31; ++k) if (f >= EB[k]) i = k;
    ibds[f] = i;
    frcs[f] = (f < 256) ? (float)(f - EB[i]) / (float)(EB[i+1] - EB[i]) : 0.f;
  }
  __syncthreads();
  const int tl = tid & 31, fo = tid >> 5;
  float* out1 = out + 16842752;
  float* out2 = out + 2*16842752;
  float* out3 = out + 3*16842752;
  const float2* sp2 = (const float2*)spec;
  {
    float p[16];
    #pragma unroll
    for (int j = 0; j < 16; ++j) p[j] = 0.f;
    for (int i = 0; i < 64; ++i){
      float a = accs[tl][i];
      const float4* wr = (const float4*)&wlo[i*128 + fo*16];
      #pragma unroll
      for (int j4 = 0; j4 < 4; ++j4){
        float4 wv = wr[j4];
        p[j4*4+0] = fmaf(a, wv.x, p[j4*4+0]);
        p[j4*4+1] = fmaf(a, wv.y, p[j4*4+1]);
        p[j4*4+2] = fmaf(a, wv.z, p[j4*4+2]);
        p[j4*4+3] = fmaf(a, wv.w, p[j4*4+3]);
      }
    }
    #pragma unroll
    for (int j = 0; j < 16; ++j){
      int f = fo*16 + j;
      int i = ibds[f]; float fr = frcs[f];
      float full = bmt[tl][i]*(1.f - fr) + bmt[tl][i+1]*fr;
      float m = fsig(p[j])*full;
      int base = (b*257 + f)*Tn + t0 + tl;
      float2 s = sp2[base];
      float fm = full*m;
      float sx = s.x*fm, sy = s.y*fm;
      __builtin_nontemporal_store(full, &out[base]);
      __builtin_nontemporal_store(m, &out1[base]);
      __builtin_nontemporal_store(sqrtf(sx*sx + sy*sy), &out2[base]);
      v2f o3; o3.x = sx; o3.y = sy;
      __builtin_nontemporal_store(o3, (v2f*)&out3[base*2]);
    }
  }
  {
    float p[16];
    #pragma unroll
    for (int j = 0; j < 16; ++j) p[j] = 0.f;
    const int g = fo >> 2, ob = (fo & 3)*16;
    for (int i = 0; i < 16; ++i){
      float a = dfhs[tl][g*16 + i];
      const float4* wr = (const float4*)&whi[(g*16 + i)*64 + ob];
      #pragma unroll
      for (int j4 = 0; j4 < 4; ++j4){
        float4 wv = wr[j4];
        p[j4*4+0] = fmaf(a, wv.x, p[j4*4+0]);
        p[j4*4+1] = fmaf(a, wv.y, p[j4*4+1]);
        p[j4*4+2] = fmaf(a, wv.z, p[j4*4+2]);
        p[j4*4+3] = fmaf(a, wv.w, p[j4*4+3]);
      }
    }
    #pragma unroll
    for (int j = 0; j < 16; ++j){
      int f = 128 + fo*16 + j;
      int i = ibds[f]; float fr = frcs[f];
      float full = bmt[tl][i]*(1.f - fr) + bmt[tl][i+1]*fr;
      float m = fsig(p[j])*full;
      int base = (b*257 + f)*Tn + t0 + tl;
      float2 s = sp2[base];
      float fm = full*m;
      float sx = s.x*fm, sy = s.y*fm;
      __builtin_nontemporal_store(full, &out[base]);
      __builtin_nontemporal_store(m, &out1[base]);
      __builtin_nontemporal_store(sqrtf(sx*sx + sy*sy), &out2[base]);
      v2f o3; o3.x = sx; o3.y = sy;
      __builtin_nontemporal_store(o3, (v2f*)&out3[base*2]);
    }
  }
  if (fo == 0){
    int base = (b*257 + 256)*Tn + t0 + tl;
    __builtin_nontemporal_store(0.f, &out[base]);
    __builtin_nontemporal_store(0.f, &out1[base]);
    __builtin_nontemporal_store(0.f, &out2[base]);
    v2f z; z.x = 0.f; z.y = 0.f;
    __builtin_nontemporal_store(z, (v2f*)&out3[base*2]);
  }
}

extern "C" void kernel_launch(void* const* d_in, const int* in_sizes, int n_in,
                              void* d_out, int out_size, void* d_ws, size_t ws_size,
                              hipStream_t stream){
  const float* mi   = (const float*)d_in[0];
  const float* spec = (const float*)d_in[1];
  const float* lpi  = (const float*)d_in[2];
  const float* s1w  = (const float*)d_in[5];
  const float* s1b  = (const float*)d_in[6];
  const float* wih0 = (const float*)d_in[7];
  const float* whh0 = (const float*)d_in[8];
  const float* bih0 = (const float*)d_in[9];
  const float* bhh0 = (const float*)d_in[10];
  const float* wih1 = (const float*)d_in[11];
  const float* whh1 = (const float*)d_in[12];
  const float* bih1 = (const float*)d_in[13];
  const float* bhh1 = (const float*)d_in[14];
  const float* fco  = (const float*)d_in[15];
  const float* filw = (const float*)d_in[16];
  const float* plo  = (const float*)d_in[17];
  const float* fihw = (const float*)d_in[18];
  const float* phi  = (const float*)d_in[19];
  const float* glw_ih = (const float*)d_in[20];
  const float* glw_hh = (const float*)d_in[21];
  const float* glb_ih = (const float*)d_in[22];
  const float* glb_hh = (const float*)d_in[23];
  const float* ghw_ih = (const float*)d_in[24];
  const float* ghw_hh = (const float*)d_in[25];
  const float* ghb_ih = (const float*)d_in[26];
  const float* ghb_hh = (const float*)d_in[27];
  const float* folw = (const float*)d_in[28];
  const float* fohw = (const float*)d_in[29];

  // big gi scratch lives in d_out (fully overwritten by k7 at the end)
  float* outf = (float*)d_out;
  float* giL  = outf;                     // [b][t][192] 12,582,912
  float* gi0w = outf + 12582912;          // [b][t][96]   6,291,456
  float* giH  = outf + 18874368;          // [b][t][96]   6,291,456

  float* ws  = (float*)d_ws;
  float* wcT = ws;                        // 6144
  float* bc  = ws + 6144;                 // 96
  float* wBT = ws + 6240;                 // 7680
  float* bB  = ws + 13920;                // 288
  float* bmA = ws + 14336;                // [b][t][32]  2,097,152
  float* acc = ws + 2111488;              // [b][t][64]  4,194,304
  float* dfh = ws + 6305792;              // [b][t][32]  2,097,152
  float* out = (float*)d_out;

  k0<<<56, 256, 0, stream>>>(s1w, s1b, wih0, bih0, glw_ih, glb_ih, ghw_ih, ghb_ih,
                             wcT, bc, wBT, bB);
  kM<<<256, 320, 0, stream>>>(mi, wcT, bc, whh0, bhh0, wih1, whh1, bih1, bhh1, fco,
                              lpi, filw, plo, fihw, phi, wBT, bB,
                              glw_ih, glw_hh, glb_ih, glb_hh, ghw_hh, ghb_hh,
                              gi0w, bmA, giL, giH, acc, dfh);
  k7<<<2048, 256, 0, stream>>>(acc, dfh, bmA, folw, fohw, spec, out);
}

// Round 11
// 596.345 us; speedup vs baseline: 1.0616x; 1.0616x over previous
//
#include <hip/hip_runtime.h>
#include <math.h>

#define Bn 256
#define Tn 256

__constant__ int EB[32] = {0,3,5,8,10,13,15,18,22,25,29,33,38,42,48,53,59,66,73,80,89,97,107,117,128,140,153,167,183,199,216,256};

__device__ __forceinline__ float fsig(float x){ return __builtin_amdgcn_rcpf(1.f + __expf(-x)); }
__device__ __forceinline__ float ftanh(float x){ return 1.f - 2.f*__builtin_amdgcn_rcpf(1.f + __expf(2.f*x)); }

__device__ __forceinline__ void gload16(const float* g, float* l){
  __builtin_amdgcn_global_load_lds((const __attribute__((address_space(1))) void*)g,
                                   (__attribute__((address_space(3))) void*)l, 16, 0, 0);
}

#define KEEP(x) asm volatile("" : "+v"(x))

// verified round-4 cross-wave exchange barrier: writer's LDS ops drained, schedule pinned,
// trailing compiler fence stops IR-level hoisting of post-barrier LDS reads.
#define XBARRIER() do{ \
  asm volatile("s_waitcnt lgkmcnt(0)" ::: "memory"); \
  __builtin_amdgcn_sched_barrier(0); \
  __builtin_amdgcn_s_barrier(); \
  __builtin_amdgcn_sched_barrier(0); \
  asm volatile("" ::: "memory"); \
}while(0)

typedef float v2f __attribute__((ext_vector_type(2)));

#define DOT16(res, X, W) do{ float _s0=0.f,_s1=0.f,_s2=0.f,_s3=0.f; \
  _Pragma("unroll") for (int _e=0;_e<4;++_e){ \
    _s0=fmaf((X)[_e],(W)[_e],_s0); _s1=fmaf((X)[4+_e],(W)[4+_e],_s1); \
    _s2=fmaf((X)[8+_e],(W)[8+_e],_s2); _s3=fmaf((X)[12+_e],(W)[12+_e],_s3);} \
  (res)=(_s0+_s1)+(_s2+_s3); }while(0)

#define DOT8(res, X, W) do{ float _s0=0.f,_s1=0.f; \
  _Pragma("unroll") for (int _e=0;_e<4;++_e){ \
    _s0=fmaf((X)[_e],(W)[_e],_s0); _s1=fmaf((X)[4+_e],(W)[4+_e],_s1);} \
  (res)=_s0+_s1; }while(0)

#define FMA44(A, X, W) do{ \
  (A)[0]=fmaf((X).x,(W)[0].x,(A)[0]); (A)[1]=fmaf((X).x,(W)[0].y,(A)[1]); (A)[2]=fmaf((X).x,(W)[0].z,(A)[2]); (A)[3]=fmaf((X).x,(W)[0].w,(A)[3]); \
  (A)[0]=fmaf((X).y,(W)[1].x,(A)[0]); (A)[1]=fmaf((X).y,(W)[1].y,(A)[1]); (A)[2]=fmaf((X).y,(W)[1].z,(A)[2]); (A)[3]=fmaf((X).y,(W)[1].w,(A)[3]); \
  (A)[0]=fmaf((X).z,(W)[2].x,(A)[0]); (A)[1]=fmaf((X).z,(W)[2].y,(A)[1]); (A)[2]=fmaf((X).z,(W)[2].z,(A)[2]); (A)[3]=fmaf((X).z,(W)[2].w,(A)[3]); \
  (A)[0]=fmaf((X).w,(W)[3].x,(A)[0]); (A)[1]=fmaf((X).w,(W)[3].y,(A)[1]); (A)[2]=fmaf((X).w,(W)[3].z,(A)[2]); (A)[3]=fmaf((X).w,(W)[3].w,(A)[3]); \
}while(0)

// ---------- k0: weight prep (unchanged, verified)
__global__ __launch_bounds__(256) void k0(const float* __restrict__ wfc, const float* __restrict__ bfc,
    const float* __restrict__ wih0, const float* __restrict__ bih0,
    const float* __restrict__ glw_ih, const float* __restrict__ glb_ih,
    const float* __restrict__ ghw_ih, const float* __restrict__ ghb_ih,
    float* __restrict__ wcT, float* __restrict__ bc,
    float* __restrict__ wBT, float* __restrict__ bB){
  int i = blockIdx.x*256 + threadIdx.x;
  if (i < 6144){
    int k = i/96, o = i - (i/96)*96;
    float s = 0.f;
    #pragma unroll
    for (int kk = 0; kk < 32; ++kk) s = fmaf(wih0[o*32+kk], wfc[kk*64+k], s);
    wcT[i] = s;
  } else if (i < 6240){
    int o = i - 6144;
    float s = bih0[o];
    #pragma unroll
    for (int kk = 0; kk < 32; ++kk) s = fmaf(wih0[o*32+kk], bfc[kk], s);
    bc[o] = s;
  } else if (i < 13920){
    int j = i - 6240;
    if (j < 6144){
      int og = j >> 7, rem = j & 127, k = rem >> 2, jj = rem & 3;
      int o = og*4 + jj; int g = o/96, r = o - g*96;
      wBT[j] = glw_ih[(g*96 + r)*32 + k];
    } else {
      int j2 = j - 6144;
      int oh = j2 >> 6, rem = j2 & 63, k = rem >> 2, jj = rem & 3;
      int o = oh*4 + jj; int g = o/48, r = o - g*48;
      wBT[j] = ghw_ih[(g*48 + r)*16 + k];
    }
  } else if (i < 14208){
    int o = i - 13920;
    bB[o] = (o < 192) ? glb_ih[o] : ghb_ih[o - 192];
  }
}

// ---------- k1: gi0[b][t][96] (unchanged, verified)
__global__ __launch_bounds__(256) void k1(const float* __restrict__ mi,
    const float* __restrict__ wcT, const float* __restrict__ bc,
    float* __restrict__ gi0){
  __shared__ float mbuf[33*36];
  const int tid = threadIdx.x;
  const int b = blockIdx.x >> 3;
  const int t0 = (blockIdx.x & 7)*32;
  const int bt0 = b*256 + t0;
  for (int idx = tid; idx < 264; idx += 256){
    int row = idx >> 3, c4 = idx & 7;
    int r = t0 - 1 + row;
    float4 v = make_float4(0.f,0.f,0.f,0.f);
    if (r >= 0) v = *(const float4*)&mi[(b*256 + r)*32 + c4*4];
    *(float4*)&mbuf[row*36 + c4*4] = v;
  }
  __syncthreads();
  const int og = tid >> 3, btg = tid & 7;
  if (og >= 24) return;
  float acc[4][4];
  #pragma unroll
  for (int bj = 0; bj < 4; ++bj){ acc[bj][0]=0.f; acc[bj][1]=0.f; acc[bj][2]=0.f; acc[bj][3]=0.f; }
  for (int fq = 0; fq < 8; ++fq){
    float4 wvp[4], wvc[4];
    #pragma unroll
    for (int i = 0; i < 4; ++i){
      int f = fq*4 + i;
      wvp[i] = *(const float4*)&wcT[(2*f)*96 + og*4];
      wvc[i] = *(const float4*)&wcT[(2*f+1)*96 + og*4];
    }
    #pragma unroll
    for (int bj = 0; bj < 4; ++bj){
      int btl = btg + 8*bj;
      float4 xp = *(const float4*)&mbuf[btl*36 + fq*4];
      float4 xc = *(const float4*)&mbuf[(btl+1)*36 + fq*4];
      FMA44(acc[bj], xp, wvp);
      FMA44(acc[bj], xc, wvc);
    }
  }
  float4 bias = *(const float4*)&bc[og*4];
  #pragma unroll
  for (int bj = 0; bj < 4; ++bj){
    int btl = btg + 8*bj;
    float4 o;
    o.x = acc[bj][0] + bias.x; o.y = acc[bj][1] + bias.y;
    o.z = acc[bj][2] + bias.z; o.w = acc[bj][3] + bias.w;
    *(float4*)&gi0[(bt0 + btl)*96 + og*4] = o;
  }
}

// ---------- kS1: stage1 double GRU + band-mask, 2 waves pipelined.
// Sandwich barrier + counted vmcnt (verified patterns).
__global__ __launch_bounds__(128,1) void kS1(const float* __restrict__ gi0,
    const float* __restrict__ whh0, const float* __restrict__ bhh0,
    const float* __restrict__ wih1, const float* __restrict__ whh1,
    const float* __restrict__ bih1, const float* __restrict__ bhh1,
    const float* __restrict__ fco, float* __restrict__ bmA)
{
  __shared__ __attribute__((aligned(16))) float gib[2][3072];
  __shared__ __attribute__((aligned(16))) float y1buf[2][32];
  __shared__ __attribute__((aligned(16))) float h1arr[32];
  __shared__ __attribute__((aligned(16))) float h2arr[32];
  const int tid = threadIdx.x;
  const int wid = tid >> 6;
  const int lane = tid & 63;
  const int q = lane >> 5, h = lane & 31, ko = q*16;
  const int b = blockIdx.x;
  const float* gsrc = gi0 + b*24576;

  float wI[3][16], wH[3][16], wF[16];
  float b0, b1, b2, b3;
  if (wid == 0){
    #pragma unroll
    for (int g = 0; g < 3; ++g){
      const float* w = whh0 + (g*32+h)*32 + ko;
      #pragma unroll
      for (int k = 0; k < 16; ++k){ wI[g][k] = w[k]; wH[g][k] = w[k]; }
    }
    #pragma unroll
    for (int k = 0; k < 16; ++k) wF[k] = 0.f;
    b0 = bhh0[h]; b1 = bhh0[32+h]; b2 = bhh0[64+h]; b3 = 0.f;
    #pragma unroll
    for (int c0 = 0; c0 < 2; ++c0)
      for (int it = 0; it < 12; ++it)
        gload16(gsrc + c0*3072 + it*256 + lane*4, &gib[c0][it*256]);
    asm volatile("s_waitcnt vmcnt(0)" ::: "memory");
  } else {
    #pragma unroll
    for (int g = 0; g < 3; ++g){
      const float* wi = wih1 + (g*32+h)*32 + ko;
      const float* wh = whh1 + (g*32+h)*32 + ko;
      #pragma unroll
      for (int k = 0; k < 16; ++k){ wI[g][k] = wi[k]; wH[g][k] = wh[k]; }
    }
    #pragma unroll
    for (int k = 0; k < 16; ++k) wF[k] = fco[(ko+k)*32 + h];
    b0 = bih1[h] + bhh1[h];
    b1 = bih1[32+h] + bhh1[32+h];
    b2 = bih1[64+h];
    b3 = bhh1[64+h];
  }
  #pragma unroll
  for (int g = 0; g < 3; ++g){
    #pragma unroll
    for (int k = 0; k < 16; ++k){ KEEP(wI[g][k]); KEEP(wH[g][k]); }
  }
  #pragma unroll
  for (int k = 0; k < 16; ++k) KEEP(wF[k]);
  __syncthreads();

  float hv[16];
  #pragma unroll
  for (int k = 0; k < 16; ++k) hv[k] = 0.f;
  float hOwn = 0.f;
  float c_r = 0.f, c_z = 0.f, c_n = 0.f, p_r = 0.f, p_z = 0.f, p_n = 0.f;

  for (int s = 0; s <= Tn; ++s){
    XBARRIER();
    if (wid == 0){
      if (s < Tn){
        const int t = s;
        if ((t & 31) == 0){
          if (t){
            int c = t >> 5;
            if (c < 7){
              for (int it = 0; it < 12; ++it)
                gload16(gsrc + (c+1)*3072 + it*256 + lane*4, &gib[(c+1)&1][it*256]);
              asm volatile("s_waitcnt vmcnt(12)" ::: "memory");
            } else {
              asm volatile("s_waitcnt vmcnt(0)" ::: "memory");
            }
          }
          const float* gt = &gib[(t>>5)&1][(t&31)*96];
          c_r = gt[h]; c_z = gt[32+h]; c_n = gt[64+h];
        } else { c_r = p_r; c_z = p_z; c_n = p_n; }
        if ((t+1) & 31){
          const float* gn = &gib[((t+1)>>5)&1][((t+1)&31)*96];
          p_r = gn[h]; p_z = gn[32+h]; p_n = gn[64+h];
        }
        float pr, pz, pn;
        DOT16(pr, hv, wI[0]); DOT16(pz, hv, wI[1]); DOT16(pn, hv, wI[2]);
        pr += __shfl_xor(pr,32); pz += __shfl_xor(pz,32); pn += __shfl_xor(pn,32);
        float r = fsig(c_r + pr + b0);
        float z = fsig(c_z + pz + b1);
        float nn = ftanh(c_n + r*(pn + b2));
        float hn = nn + z*(hOwn - nn);
        hOwn = hn;
        h1arr[h] = hn;
        if (q == 0) y1buf[s & 1][h] = hn;
        *(float4*)&hv[0]  = *(const float4*)&h1arr[ko+0];
        *(float4*)&hv[4]  = *(const float4*)&h1arr[ko+4];
        *(float4*)&hv[8]  = *(const float4*)&h1arr[ko+8];
        *(float4*)&hv[12] = *(const float4*)&h1arr[ko+12];
      }
    } else {
      if (s >= 1){
        const int t = s - 1;
        const float* yb = y1buf[t & 1];
        float xv[16];
        *(float4*)&xv[0]  = *(const float4*)&yb[ko+0];
        *(float4*)&xv[4]  = *(const float4*)&yb[ko+4];
        *(float4*)&xv[8]  = *(const float4*)&yb[ko+8];
        *(float4*)&xv[12] = *(const float4*)&yb[ko+12];
        float ur, uz, ui, vr, vz, vh;
        DOT16(ur, xv, wI[0]); DOT16(uz, xv, wI[1]); DOT16(ui, xv, wI[2]);
        DOT16(vr, hv, wH[0]); DOT16(vz, hv, wH[1]); DOT16(vh, hv, wH[2]);
        float qr = ur + vr, qz = uz + vz;
        qr += __shfl_xor(qr,32); qz += __shfl_xor(qz,32);
        ui += __shfl_xor(ui,32); vh += __shfl_xor(vh,32);
        float r1 = fsig(qr + b0);
        float z1 = fsig(qz + b1);
        float n1 = ftanh(ui + b2 + r1*(vh + b3));
        float hn = n1 + z1*(hOwn - n1);
        hOwn = hn;
        h2arr[h] = hn;
        *(float4*)&hv[0]  = *(const float4*)&h2arr[ko+0];
        *(float4*)&hv[4]  = *(const float4*)&h2arr[ko+4];
        *(float4*)&hv[8]  = *(const float4*)&h2arr[ko+8];
        *(float4*)&hv[12] = *(const float4*)&h2arr[ko+12];
        float sf = 0.f;
        #pragma unroll
        for (int k = 0; k < 16; ++k) sf = fmaf(xv[k] + hv[k], wF[k], sf);
        sf += __shfl_xor(sf,32);
        if (q == 0) bmA[(b*Tn + t)*32 + h] = fsig(sf);
      }
    }
  }
}

// ---------- kP: fused low/high fc_in + PReLU + gi projections (unchanged, verified)
__global__ __launch_bounds__(256) void kP(const float* __restrict__ lpi,
    const float* __restrict__ bmA,
    const float* __restrict__ wlo, const float* __restrict__ plo,
    const float* __restrict__ whi, const float* __restrict__ phi,
    const float* __restrict__ wBT, const float* __restrict__ bB,
    float* __restrict__ giL, float* __restrict__ giH)
{
  __shared__ float xb[32*292];
  __shared__ float mb[32*100];
  const int tid = threadIdx.x;
  const int b = blockIdx.x >> 3;
  const int t0 = (blockIdx.x & 7)*32;
  const int bt0 = b*256 + t0;
  #pragma unroll
  for (int j = 0; j < 8; ++j){
    int idx = j*256 + tid;
    int row = idx >> 6, c4 = idx & 63;
    float4 v = *(const float4*)&lpi[(bt0 + row)*256 + c4*4];
    *(float4*)&xb[row*292 + c4*4] = v;
  }
  {
    int row = tid >> 3, c4 = tid & 7;
    float4 v = *(const float4*)&bmA[(bt0 + row)*32 + c4*4];
    *(float4*)&xb[row*292 + 256 + c4*4] = v;
  }
  __syncthreads();
  const int og = tid >> 3, btg = tid & 7;
  if (og < 16){
    float acc[4][4];
    #pragma unroll
    for (int bj = 0; bj < 4; ++bj){ acc[bj][0]=0.f; acc[bj][1]=0.f; acc[bj][2]=0.f; acc[bj][3]=0.f; }
    for (int kq = 0; kq < 40; ++kq){
      int k0_ = kq*4;
      int kk = (k0_ < 128) ? k0_ : k0_ + 128;
      float4 wv[4];
      #pragma unroll
      for (int i = 0; i < 4; ++i) wv[i] = *(const float4*)&wlo[(k0_+i)*64 + og*4];
      #pragma unroll
      for (int bj = 0; bj < 4; ++bj){
        float4 xv = *(const float4*)&xb[(btg + 8*bj)*292 + kk];
        FMA44(acc[bj], xv, wv);
      }
    }
    const float a = plo[0];
    #pragma unroll
    for (int bj = 0; bj < 4; ++bj){
      float4 m;
      m.x = acc[bj][0] >= 0.f ? acc[bj][0] : a*acc[bj][0];
      m.y = acc[bj][1] >= 0.f ? acc[bj][1] : a*acc[bj][1];
      m.z = acc[bj][2] >= 0.f ? acc[bj][2] : a*acc[bj][2];
      m.w = acc[bj][3] >= 0.f ? acc[bj][3] : a*acc[bj][3];
      *(float4*)&mb[(btg + 8*bj)*100 + og*4] = m;
    }
  } else if (og < 24){
    int o0 = (og - 16)*4;
    int g = o0 >> 4, r0 = o0 & 15;
    int xoff = 128 + g*80;
    float acc[4][4];
    #pragma unroll
    for (int bj = 0; bj < 4; ++bj){ acc[bj][0]=0.f; acc[bj][1]=0.f; acc[bj][2]=0.f; acc[bj][3]=0.f; }
    for (int kq = 0; kq < 20; ++kq){
      int k0_ = kq*4;
      float4 wv[4];
      #pragma unroll
      for (int i = 0; i < 4; ++i) wv[i] = *(const float4*)&whi[(g*80 + k0_ + i)*16 + r0];
      #pragma unroll
      for (int bj = 0; bj < 4; ++bj){
        float4 xv = *(const float4*)&xb[(btg + 8*bj)*292 + xoff + k0_];
        FMA44(acc[bj], xv, wv);
      }
    }
    const float a = phi[0];
    #pragma unroll
    for (int bj = 0; bj < 4; ++bj){
      float4 m;
      m.x = acc[bj][0] >= 0.f ? acc[bj][0] : a*acc[bj][0];
      m.y = acc[bj][1] >= 0.f ? acc[bj][1] : a*acc[bj][1];
      m.z = acc[bj][2] >= 0.f ? acc[bj][2] : a*acc[bj][2];
      m.w = acc[bj][3] >= 0.f ? acc[bj][3] : a*acc[bj][3];
      *(float4*)&mb[(btg + 8*bj)*100 + 64 + o0] = m;
    }
  }
  __syncthreads();
  for (int og2 = og; og2 < 72; og2 += 32){
    int woff, kbase, K, obase, dstride;
    float* dst;
    float4 bias;
    if (og2 < 48){
      woff = og2*128; kbase = (og2 >= 24) ? 32 : 0; K = 32;
      obase = og2*4; dst = giL; dstride = 192;
      bias = *(const float4*)&bB[obase];
    } else {
      int oh = og2 - 48;
      woff = 6144 + oh*64;
      int o0 = oh*4; int g = o0/48;
      kbase = 64 + g*16; K = 16;
      obase = o0; dst = giH; dstride = 96;
      bias = *(const float4*)&bB[192 + o0];
    }
    float acc[4][4];
    #pragma unroll
    for (int bj = 0; bj < 4; ++bj){ acc[bj][0]=0.f; acc[bj][1]=0.f; acc[bj][2]=0.f; acc[bj][3]=0.f; }
    for (int kq = 0; kq < K/4; ++kq){
      float4 wv[4];
      #pragma unroll
      for (int i = 0; i < 4; ++i) wv[i] = *(const float4*)&wBT[woff + (kq*4 + i)*4];
      #pragma unroll
      for (int bj = 0; bj < 4; ++bj){
        float4 xv = *(const float4*)&mb[(btg + 8*bj)*100 + kbase + kq*4];
        FMA44(acc[bj], xv, wv);
      }
    }
    #pragma unroll
    for (int bj = 0; bj < 4; ++bj){
      int btl = btg + 8*bj;
      float4 o;
      o.x = acc[bj][0] + bias.x; o.y = acc[bj][1] + bias.y;
      o.z = acc[bj][2] + bias.z; o.w = acc[bj][3] + bias.w;
      *(float4*)&dst[(bt0 + btl)*dstride + obase] = o;
    }
  }
}

// ---------- kR2: blocks 0..255 = low 2-layer GRU pipelined (4 waves);
// blocks 256..319 = high GRU (4 independent waves). Sandwich barrier + counted vmcnt.
__global__ __launch_bounds__(256,1) void kR2(const float* __restrict__ giL,
    const float* __restrict__ giH,
    const float* __restrict__ wihL, const float* __restrict__ whhL,
    const float* __restrict__ bihL, const float* __restrict__ bhhL,
    const float* __restrict__ whhH, const float* __restrict__ bhhH,
    float* __restrict__ acc, float* __restrict__ dfh)
{
  __shared__ __attribute__((aligned(16))) float smem[12544];
  const int tid = threadIdx.x;
  const int wid = tid >> 6;
  const int lane = tid & 63;
  if (blockIdx.x < 256){
    const int role = wid >> 1;
    const int g = wid & 1;
    const int q = lane >> 5, h = lane & 31, ko = q*16;
    const int b = blockIdx.x;
    float* gib   = smem + g*6144;
    float* y0buf = smem + 12288;
    float* h0arr = smem + 12416 + g*32;
    float* h1l   = smem + 12480;
    const float* gsrc = giL + b*49152 + g*96;

    float wI[3][16], wH[3][16];
    float b0, b1, b2, b3;
    if (role == 0){
      #pragma unroll
      for (int gt = 0; gt < 3; ++gt){
        const float* w = whhL + (g*96 + gt*32 + h)*32 + ko;
        #pragma unroll
        for (int k = 0; k < 16; ++k){ wI[gt][k] = w[k]; wH[gt][k] = w[k]; }
      }
      b0 = bhhL[g*96+h]; b1 = bhhL[g*96+32+h]; b2 = bhhL[g*96+64+h]; b3 = 0.f;
      #pragma unroll
      for (int c0 = 0; c0 < 2; ++c0)
        for (int it = 0; it < 12; ++it){
          int i = it*64 + lane;
          int toff = i/24, c4 = i - toff*24;
          gload16(gsrc + (c0*32 + toff)*192 + c4*4, &gib[c0*3072 + it*256]);
        }
      asm volatile("s_waitcnt vmcnt(0)" ::: "memory");
    } else {
      #pragma unroll
      for (int gt = 0; gt < 3; ++gt){
        const float* wi = wihL + ((2+g)*96 + gt*32 + h)*32 + ko;
        const float* wh = whhL + ((2+g)*96 + gt*32 + h)*32 + ko;
        #pragma unroll
        for (int k = 0; k < 16; ++k){ wI[gt][k] = wi[k]; wH[gt][k] = wh[k]; }
      }
      b0 = bihL[(2+g)*96+h]    + bhhL[(2+g)*96+h];
      b1 = bihL[(2+g)*96+32+h] + bhhL[(2+g)*96+32+h];
      b2 = bihL[(2+g)*96+64+h];
      b3 = bhhL[(2+g)*96+64+h];
    }
    #pragma unroll
    for (int gt = 0; gt < 3; ++gt){
      #pragma unroll
      for (int k = 0; k < 16; ++k){ KEEP(wI[gt][k]); KEEP(wH[gt][k]); }
    }
    __syncthreads();

    float hv[16];
    #pragma unroll
    for (int k = 0; k < 16; ++k) hv[k] = 0.f;
    float hOwn = 0.f;
    float c_r = 0.f, c_z = 0.f, c_n = 0.f, p_r = 0.f, p_z = 0.f, p_n = 0.f;
    const int spos = ((h&1)<<5) + (g<<4) + (h>>1);

    for (int s = 0; s <= Tn; ++s){
      XBARRIER();
      if (role == 0){
        if (s < Tn){
          const int t = s;
          if ((t & 31) == 0){
            if (t){
              int c = t >> 5;
              if (c < 7){
                for (int it = 0; it < 12; ++it){
                  int i = it*64 + lane;
                  int toff = i/24, c4 = i - toff*24;
                  gload16(gsrc + ((c+1)*32 + toff)*192 + c4*4, &gib[((c+1)&1)*3072 + it*256]);
                }
                asm volatile("s_waitcnt vmcnt(12)" ::: "memory");
              } else {
                asm volatile("s_waitcnt vmcnt(0)" ::: "memory");
              }
            }
            const float* gt = &gib[((t>>5)&1)*3072 + (t&31)*96];
            c_r = gt[h]; c_z = gt[32+h]; c_n = gt[64+h];
          } else { c_r = p_r; c_z = p_z; c_n = p_n; }
          if ((t+1) & 31){
            const float* gn = &gib[(((t+1)>>5)&1)*3072 + ((t+1)&31)*96];
            p_r = gn[h]; p_z = gn[32+h]; p_n = gn[64+h];
          }
          float pr, pz, pn;
          DOT16(pr, hv, wI[0]); DOT16(pz, hv, wI[1]); DOT16(pn, hv, wI[2]);
          pr += __shfl_xor(pr,32); pz += __shfl_xor(pz,32); pn += __shfl_xor(pn,32);
          float r = fsig(c_r + pr + b0);
          float z = fsig(c_z + pz + b1);
          float nn = ftanh(c_n + r*(pn + b2));
          float hn = nn + z*(hOwn - nn);
          hOwn = hn;
          h0arr[h] = hn;
          if (q == 0) y0buf[(s&1)*64 + spos] = hn;
          *(float4*)&hv[0]  = *(const float4*)&h0arr[ko+0];
          *(float4*)&hv[4]  = *(const float4*)&h0arr[ko+4];
          *(float4*)&hv[8]  = *(const float4*)&h0arr[ko+8];
          *(float4*)&hv[12] = *(const float4*)&h0arr[ko+12];
        }
      } else {
        if (s >= 1){
          const int t = s - 1;
          const float* yb = &y0buf[(t&1)*64];
          float xv[16];
          *(float4*)&xv[0]  = *(const float4*)&yb[g*32 + ko + 0];
          *(float4*)&xv[4]  = *(const float4*)&yb[g*32 + ko + 4];
          *(float4*)&xv[8]  = *(const float4*)&yb[g*32 + ko + 8];
          *(float4*)&xv[12] = *(const float4*)&yb[g*32 + ko + 12];
          float yown = yb[g*32 + h];
          float ur, uz, ui, vr, vz, vh;
          DOT16(ur, xv, wI[0]); DOT16(uz, xv, wI[1]); DOT16(ui, xv, wI[2]);
          DOT16(vr, hv, wH[0]); DOT16(vz, hv, wH[1]); DOT16(vh, hv, wH[2]);
          float qr = ur + vr, qz = uz + vz;
          qr += __shfl_xor(qr,32); qz += __shfl_xor(qz,32);
          ui += __shfl_xor(ui,32); vh += __shfl_xor(vh,32);
          float r1 = fsig(qr + b0);
          float z1 = fsig(qz + b1);
          float n1 = ftanh(ui + b2 + r1*(vh + b3));
          float hn = n1 + z1*(hOwn - n1);
          hOwn = hn;
          h1l[g*32 + h] = hn;
          *(float4*)&hv[0]  = *(const float4*)&h1l[g*32 + ko+0];
          *(float4*)&hv[4]  = *(const float4*)&h1l[g*32 + ko+4];
          *(float4*)&hv[8]  = *(const float4*)&h1l[g*32 + ko+8];
          *(float4*)&hv[12] = *(const float4*)&h1l[g*32 + ko+12];
          if (q == 0) acc[(b*256 + t)*64 + g*32 + h] = yown + hn;
        }
      }
    }
  } else {
    // ---------- high path: 4 independent waves, chunk-16, no barriers
    const int g = lane >> 5, qh = (lane >> 4) & 1, h = lane & 15, ko = qh*8;
    const int b = (blockIdx.x - 256)*4 + wid;
    float* gib  = smem + wid*3072;
    float* harr = smem + 12288 + wid*32;
    float ah[3][8];
    #pragma unroll
    for (int gt = 0; gt < 3; ++gt){
      const float* wp = whhH + (g*48 + gt*16 + h)*16 + ko;
      #pragma unroll
      for (int k = 0; k < 8; ++k) ah[gt][k] = wp[k];
    }
    #pragma unroll
    for (int gt = 0; gt < 3; ++gt){
      #pragma unroll
      for (int k = 0; k < 8; ++k) KEEP(ah[gt][k]);
    }
    const float bhr = bhhH[g*48+h], bhz = bhhH[g*48+16+h], bhn = bhhH[g*48+32+h];
    const float* gsrc = giH + b*24576;
    #pragma unroll
    for (int c0 = 0; c0 < 2; ++c0)
      for (int it = 0; it < 6; ++it)
        gload16(gsrc + c0*1536 + it*256 + lane*4, &gib[c0*1536 + it*256]);
    asm volatile("s_waitcnt vmcnt(0)" ::: "memory");

    float hv[8];
    #pragma unroll
    for (int k = 0; k < 8; ++k) hv[k] = 0.f;
    float hOwn = 0.f;
    float c_r = 0.f, c_z = 0.f, c_n = 0.f, p_r = 0.f, p_z = 0.f, p_n = 0.f;

    for (int t = 0; t < Tn; ++t){
      if ((t & 15) == 0){
        if (t){
          int c = t >> 4;
          if (c < 15){
            const float* gs = gsrc + (c+1)*1536;
            for (int it = 0; it < 6; ++it)
              gload16(gs + it*256 + lane*4, &gib[((c+1)&1)*1536 + it*256]);
            asm volatile("s_waitcnt vmcnt(6)" ::: "memory");
          } else {
            asm volatile("s_waitcnt vmcnt(0)" ::: "memory");
          }
        }
        const float* gt = &gib[((t>>4)&1)*1536 + (t&15)*96 + g*48];
        c_r = gt[h]; c_z = gt[16+h]; c_n = gt[32+h];
      } else { c_r = p_r; c_z = p_z; c_n = p_n; }
      if ((t+1) & 15){
        const float* gn = &gib[(((t+1)>>4)&1)*1536 + ((t+1)&15)*96 + g*48];
        p_r = gn[h]; p_z = gn[16+h]; p_n = gn[32+h];
      }
      float pr, pz, pn;
      DOT8(pr, hv, ah[0]); DOT8(pz, hv, ah[1]); DOT8(pn, hv, ah[2]);
      pr += __shfl_xor(pr,16); pz += __shfl_xor(pz,16); pn += __shfl_xor(pn,16);
      float r = fsig(c_r + pr + bhr);
      float z = fsig(c_z + pz + bhz);
      float nn = ftanh(c_n + r*(pn + bhn));
      float hn = nn + z*(hOwn - nn);
      hOwn = hn;
      harr[g*16 + h] = hn;
      *(float4*)&hv[0] = *(const float4*)&harr[g*16 + ko + 0];
      *(float4*)&hv[4] = *(const float4*)&harr[g*16 + ko + 4];
      if (qh == 0) dfh[(b*256 + t)*32 + g*16 + h] = hn;
    }
  }
}

// ---------- k7: register-resident masks + nontemporal stores (unchanged, verified)
__global__ __launch_bounds__(256) void k7(const float* __restrict__ acc,
    const float* __restrict__ dfh, const float* __restrict__ bmA,
    const float* __restrict__ wlo, const float* __restrict__ whi,
    const float* __restrict__ spec, float* __restrict__ out)
{
  __shared__ float accs[32][65];
  __shared__ float dfhs[32][33];
  __shared__ float bmt[32][33];
  __shared__ float frcs[257];
  __shared__ int   ibds[257];
  const int tid = threadIdx.x;
  const int b  = blockIdx.x >> 3;
  const int t0 = (blockIdx.x & 7) * 32;
  for (int idx = tid; idx < 32*16; idx += 256){
    int tl = idx >> 4, c4 = (idx & 15)*4;
    float4 v = *(const float4*)&acc[(b*256 + t0 + tl)*64 + c4];
    accs[tl][c4] = v.x; accs[tl][c4+1] = v.y; accs[tl][c4+2] = v.z; accs[tl][c4+3] = v.w;
  }
  for (int idx = tid; idx < 32*8; idx += 256){
    int tl = idx >> 3, c4 = (idx & 7)*4;
    float4 v = *(const float4*)&dfh[(b*256 + t0 + tl)*32 + c4];
    dfhs[tl][c4] = v.x; dfhs[tl][c4+1] = v.y; dfhs[tl][c4+2] = v.z; dfhs[tl][c4+3] = v.w;
    float4 u = *(const float4*)&bmA[(b*Tn + t0 + tl)*32 + c4];
    bmt[tl][c4] = u.x; bmt[tl][c4+1] = u.y; bmt[tl][c4+2] = u.z; bmt[tl][c4+3] = u.w;
  }
  for (int f = tid; f < 257; f += 256){
    int i = 0;
    #pragma unroll
    for (int k = 1; k < 31; ++k) if (f >= EB[k]) i = k;
    ibds[f] = i;
    frcs[f] = (f < 256) ? (float)(f - EB[i]) / (float)(EB[i+1] - EB[i]) : 0.f;
  }
  __syncthreads();
  const int tl = tid & 31, fo = tid >> 5;
  float* out1 = out + 16842752;
  float* out2 = out + 2*16842752;
  float* out3 = out + 3*16842752;
  const float2* sp2 = (const float2*)spec;
  {
    float p[16];
    #pragma unroll
    for (int j = 0; j < 16; ++j) p[j] = 0.f;
    for (int i = 0; i < 64; ++i){
      float a = accs[tl][i];
      const float4* wr = (const float4*)&wlo[i*128 + fo*16];
      #pragma unroll
      for (int j4 = 0; j4 < 4; ++j4){
        float4 wv = wr[j4];
        p[j4*4+0] = fmaf(a, wv.x, p[j4*4+0]);
        p[j4*4+1] = fmaf(a, wv.y, p[j4*4+1]);
        p[j4*4+2] = fmaf(a, wv.z, p[j4*4+2]);
        p[j4*4+3] = fmaf(a, wv.w, p[j4*4+3]);
      }
    }
    #pragma unroll
    for (int j = 0; j < 16; ++j){
      int f = fo*16 + j;
      int i = ibds[f]; float fr = frcs[f];
      float full = bmt[tl][i]*(1.f - fr) + bmt[tl][i+1]*fr;
      float m = fsig(p[j])*full;
      int base = (b*257 + f)*Tn + t0 + tl;
      float2 s = sp2[base];
      float fm = full*m;
      float sx = s.x*fm, sy = s.y*fm;
      __builtin_nontemporal_store(full, &out[base]);
      __builtin_nontemporal_store(m, &out1[base]);
      __builtin_nontemporal_store(sqrtf(sx*sx + sy*sy), &out2[base]);
      v2f o3; o3.x = sx; o3.y = sy;
      __builtin_nontemporal_store(o3, (v2f*)&out3[base*2]);
    }
  }
  {
    float p[16];
    #pragma unroll
    for (int j = 0; j < 16; ++j) p[j] = 0.f;
    const int g = fo >> 2, ob = (fo & 3)*16;
    for (int i = 0; i < 16; ++i){
      float a = dfhs[tl][g*16 + i];
      const float4* wr = (const float4*)&whi[(g*16 + i)*64 + ob];
      #pragma unroll
      for (int j4 = 0; j4 < 4; ++j4){
        float4 wv = wr[j4];
        p[j4*4+0] = fmaf(a, wv.x, p[j4*4+0]);
        p[j4*4+1] = fmaf(a, wv.y, p[j4*4+1]);
        p[j4*4+2] = fmaf(a, wv.z, p[j4*4+2]);
        p[j4*4+3] = fmaf(a, wv.w, p[j4*4+3]);
      }
    }
    #pragma unroll
    for (int j = 0; j < 16; ++j){
      int f = 128 + fo*16 + j;
      int i = ibds[f]; float fr = frcs[f];
      float full = bmt[tl][i]*(1.f - fr) + bmt[tl][i+1]*fr;
      float m = fsig(p[j])*full;
      int base = (b*257 + f)*Tn + t0 + tl;
      float2 s = sp2[base];
      float fm = full*m;
      float sx = s.x*fm, sy = s.y*fm;
      __builtin_nontemporal_store(full, &out[base]);
      __builtin_nontemporal_store(m, &out1[base]);
      __builtin_nontemporal_store(sqrtf(sx*sx + sy*sy), &out2[base]);
      v2f o3; o3.x = sx; o3.y = sy;
      __builtin_nontemporal_store(o3, (v2f*)&out3[base*2]);
    }
  }
  if (fo == 0){
    int base = (b*257 + 256)*Tn + t0 + tl;
    __builtin_nontemporal_store(0.f, &out[base]);
    __builtin_nontemporal_store(0.f, &out1[base]);
    __builtin_nontemporal_store(0.f, &out2[base]);
    v2f z; z.x = 0.f; z.y = 0.f;
    __builtin_nontemporal_store(z, (v2f*)&out3[base*2]);
  }
}

extern "C" void kernel_launch(void* const* d_in, const int* in_sizes, int n_in,
                              void* d_out, int out_size, void* d_ws, size_t ws_size,
                              hipStream_t stream){
  const float* mi   = (const float*)d_in[0];
  const float* spec = (const float*)d_in[1];
  const float* lpi  = (const float*)d_in[2];
  const float* s1w  = (const float*)d_in[5];
  const float* s1b  = (const float*)d_in[6];
  const float* wih0 = (const float*)d_in[7];
  const float* whh0 = (const float*)d_in[8];
  const float* bih0 = (const float*)d_in[9];
  const float* bhh0 = (const float*)d_in[10];
  const float* wih1 = (const float*)d_in[11];
  const float* whh1 = (const float*)d_in[12];
  const float* bih1 = (const float*)d_in[13];
  const float* bhh1 = (const float*)d_in[14];
  const float* fco  = (const float*)d_in[15];
  const float* filw = (const float*)d_in[16];
  const float* plo  = (const float*)d_in[17];
  const float* fihw = (const float*)d_in[18];
  const float* phi  = (const float*)d_in[19];
  const float* glw_ih = (const float*)d_in[20];
  const float* glw_hh = (const float*)d_in[21];
  const float* glb_ih = (const float*)d_in[22];
  const float* glb_hh = (const float*)d_in[23];
  const float* ghw_ih = (const float*)d_in[24];
  const float* ghw_hh = (const float*)d_in[25];
  const float* ghb_ih = (const float*)d_in[26];
  const float* ghb_hh = (const float*)d_in[27];
  const float* folw = (const float*)d_in[28];
  const float* fohw = (const float*)d_in[29];

  // big gi scratch lives in d_out (fully overwritten by k7 at the end)
  float* outf = (float*)d_out;
  float* giL  = outf;                     // [b][t][192] 12,582,912
  float* gi0  = outf + 12582912;          // [b][t][96]   6,291,456
  float* giH  = outf + 18874368;          // [b][t][96]   6,291,456

  float* ws  = (float*)d_ws;
  float* wcT = ws;                        // 6144
  float* bc  = ws + 6144;                 // 96
  float* wBT = ws + 6240;                 // 7680
  float* bB  = ws + 13920;                // 288
  float* bmA = ws + 14336;                // [b][t][32]  2,097,152
  float* acc = ws + 2111488;              // [b][t][64]  4,194,304
  float* dfh = ws + 6305792;              // [b][t][32]  2,097,152
  float* out = (float*)d_out;

  k0<<<56, 256, 0, stream>>>(s1w, s1b, wih0, bih0, glw_ih, glb_ih, ghw_ih, ghb_ih,
                             wcT, bc, wBT, bB);
  k1<<<2048, 256, 0, stream>>>(mi, wcT, bc, gi0);
  kS1<<<256, 128, 0, stream>>>(gi0, whh0, bhh0, wih1, whh1, bih1, bhh1, fco, bmA);
  kP<<<2048, 256, 0, stream>>>(lpi, bmA, filw, plo, fihw, phi, wBT, bB, giL, giH);
  kR2<<<320, 256, 0, stream>>>(giL, giH, glw_ih, glw_hh, glb_ih, glb_hh,
                               ghw_hh, ghb_hh, acc, dfh);
  k7<<<2048, 256, 0, stream>>>(acc, dfh, bmA, folw, fohw, spec, out);
}

// Round 12
// 584.050 us; speedup vs baseline: 1.0839x; 1.0211x over previous
//
#include <hip/hip_runtime.h>
#include <math.h>

#define Bn 256
#define Tn 256

__constant__ int EB[32] = {0,3,5,8,10,13,15,18,22,25,29,33,38,42,48,53,59,66,73,80,89,97,107,117,128,140,153,167,183,199,216,256};

__device__ __forceinline__ float fsig(float x){ return __builtin_amdgcn_rcpf(1.f + __expf(-x)); }
__device__ __forceinline__ float ftanh(float x){ return 1.f - 2.f*__builtin_amdgcn_rcpf(1.f + __expf(2.f*x)); }

__device__ __forceinline__ void gload16(const float* g, float* l){
  __builtin_amdgcn_global_load_lds((const __attribute__((address_space(1))) void*)g,
                                   (__attribute__((address_space(3))) void*)l, 16, 0, 0);
}

#define KEEP(x) asm volatile("" : "+v"(x))

typedef float v2f __attribute__((ext_vector_type(2)));

#define DOT16(res, X, W) do{ float _s0=0.f,_s1=0.f,_s2=0.f,_s3=0.f; \
  _Pragma("unroll") for (int _e=0;_e<4;++_e){ \
    _s0=fmaf((X)[_e],(W)[_e],_s0); _s1=fmaf((X)[4+_e],(W)[4+_e],_s1); \
    _s2=fmaf((X)[8+_e],(W)[8+_e],_s2); _s3=fmaf((X)[12+_e],(W)[12+_e],_s3);} \
  (res)=(_s0+_s1)+(_s2+_s3); }while(0)

#define DOT8(res, X, W) do{ float _s0=0.f,_s1=0.f; \
  _Pragma("unroll") for (int _e=0;_e<4;++_e){ \
    _s0=fmaf((X)[_e],(W)[_e],_s0); _s1=fmaf((X)[4+_e],(W)[4+_e],_s1);} \
  (res)=_s0+_s1; }while(0)

#define FMA44(A, X, W) do{ \
  (A)[0]=fmaf((X).x,(W)[0].x,(A)[0]); (A)[1]=fmaf((X).x,(W)[0].y,(A)[1]); (A)[2]=fmaf((X).x,(W)[0].z,(A)[2]); (A)[3]=fmaf((X).x,(W)[0].w,(A)[3]); \
  (A)[0]=fmaf((X).y,(W)[1].x,(A)[0]); (A)[1]=fmaf((X).y,(W)[1].y,(A)[1]); (A)[2]=fmaf((X).y,(W)[1].z,(A)[2]); (A)[3]=fmaf((X).y,(W)[1].w,(A)[3]); \
  (A)[0]=fmaf((X).z,(W)[2].x,(A)[0]); (A)[1]=fmaf((X).z,(W)[2].y,(A)[1]); (A)[2]=fmaf((X).z,(W)[2].z,(A)[2]); (A)[3]=fmaf((X).z,(W)[2].w,(A)[3]); \
  (A)[0]=fmaf((X).w,(W)[3].x,(A)[0]); (A)[1]=fmaf((X).w,(W)[3].y,(A)[1]); (A)[2]=fmaf((X).w,(W)[3].z,(A)[2]); (A)[3]=fmaf((X).w,(W)[3].w,(A)[3]); \
}while(0)

// ---------- k0: weight prep (unchanged, verified)
__global__ __launch_bounds__(256) void k0(const float* __restrict__ wfc, const float* __restrict__ bfc,
    const float* __restrict__ wih0, const float* __restrict__ bih0,
    const float* __restrict__ glw_ih, const float* __restrict__ glb_ih,
    const float* __restrict__ ghw_ih, const float* __restrict__ ghb_ih,
    float* __restrict__ wcT, float* __restrict__ bc,
    float* __restrict__ wBT, float* __restrict__ bB){
  int i = blockIdx.x*256 + threadIdx.x;
  if (i < 6144){
    int k = i/96, o = i - (i/96)*96;
    float s = 0.f;
    #pragma unroll
    for (int kk = 0; kk < 32; ++kk) s = fmaf(wih0[o*32+kk], wfc[kk*64+k], s);
    wcT[i] = s;
  } else if (i < 6240){
    int o = i - 6144;
    float s = bih0[o];
    #pragma unroll
    for (int kk = 0; kk < 32; ++kk) s = fmaf(wih0[o*32+kk], bfc[kk], s);
    bc[o] = s;
  } else if (i < 13920){
    int j = i - 6240;
    if (j < 6144){
      int og = j >> 7, rem = j & 127, k = rem >> 2, jj = rem & 3;
      int o = og*4 + jj; int g = o/96, r = o - g*96;
      wBT[j] = glw_ih[(g*96 + r)*32 + k];
    } else {
      int j2 = j - 6144;
      int oh = j2 >> 6, rem = j2 & 63, k = rem >> 2, jj = rem & 3;
      int o = oh*4 + jj; int g = o/48, r = o - g*48;
      wBT[j] = ghw_ih[(g*48 + r)*16 + k];
    }
  } else if (i < 14208){
    int o = i - 13920;
    bB[o] = (o < 192) ? glb_ih[o] : ghb_ih[o - 192];
  }
}

// ---------- k1: gi0[b][t][96] (unchanged, verified)
__global__ __launch_bounds__(256) void k1(const float* __restrict__ mi,
    const float* __restrict__ wcT, const float* __restrict__ bc,
    float* __restrict__ gi0){
  __shared__ float mbuf[33*36];
  const int tid = threadIdx.x;
  const int b = blockIdx.x >> 3;
  const int t0 = (blockIdx.x & 7)*32;
  const int bt0 = b*256 + t0;
  for (int idx = tid; idx < 264; idx += 256){
    int row = idx >> 3, c4 = idx & 7;
    int r = t0 - 1 + row;
    float4 v = make_float4(0.f,0.f,0.f,0.f);
    if (r >= 0) v = *(const float4*)&mi[(b*256 + r)*32 + c4*4];
    *(float4*)&mbuf[row*36 + c4*4] = v;
  }
  __syncthreads();
  const int og = tid >> 3, btg = tid & 7;
  if (og >= 24) return;
  float acc[4][4];
  #pragma unroll
  for (int bj = 0; bj < 4; ++bj){ acc[bj][0]=0.f; acc[bj][1]=0.f; acc[bj][2]=0.f; acc[bj][3]=0.f; }
  for (int fq = 0; fq < 8; ++fq){
    float4 wvp[4], wvc[4];
    #pragma unroll
    for (int i = 0; i < 4; ++i){
      int f = fq*4 + i;
      wvp[i] = *(const float4*)&wcT[(2*f)*96 + og*4];
      wvc[i] = *(const float4*)&wcT[(2*f+1)*96 + og*4];
    }
    #pragma unroll
    for (int bj = 0; bj < 4; ++bj){
      int btl = btg + 8*bj;
      float4 xp = *(const float4*)&mbuf[btl*36 + fq*4];
      float4 xc = *(const float4*)&mbuf[(btl+1)*36 + fq*4];
      FMA44(acc[bj], xp, wvp);
      FMA44(acc[bj], xc, wvc);
    }
  }
  float4 bias = *(const float4*)&bc[og*4];
  #pragma unroll
  for (int bj = 0; bj < 4; ++bj){
    int btl = btg + 8*bj;
    float4 o;
    o.x = acc[bj][0] + bias.x; o.y = acc[bj][1] + bias.y;
    o.z = acc[bj][2] + bias.z; o.w = acc[bj][3] + bias.w;
    *(float4*)&gi0[(bt0 + btl)*96 + og*4] = o;
  }
}

// ---------- kS1: stage1 double GRU + band-mask, 2 waves pipelined (round-9 verified)
__global__ __launch_bounds__(128,1) void kS1(const float* __restrict__ gi0,
    const float* __restrict__ whh0, const float* __restrict__ bhh0,
    const float* __restrict__ wih1, const float* __restrict__ whh1,
    const float* __restrict__ bih1, const float* __restrict__ bhh1,
    const float* __restrict__ fco, float* __restrict__ bmA)
{
  __shared__ __attribute__((aligned(16))) float gib[2][3072];
  __shared__ __attribute__((aligned(16))) float y1buf[2][32];
  __shared__ __attribute__((aligned(16))) float h1arr[32];
  __shared__ __attribute__((aligned(16))) float h2arr[32];
  const int tid = threadIdx.x;
  const int wid = tid >> 6;
  const int lane = tid & 63;
  const int q = lane >> 5, h = lane & 31, ko = q*16;
  const int b = blockIdx.x;
  const float* gsrc = gi0 + b*24576;

  float wI[3][16], wH[3][16], wF[16];
  float b0, b1, b2, b3;
  if (wid == 0){
    #pragma unroll
    for (int g = 0; g < 3; ++g){
      const float* w = whh0 + (g*32+h)*32 + ko;
      #pragma unroll
      for (int k = 0; k < 16; ++k){ wI[g][k] = w[k]; wH[g][k] = w[k]; }
    }
    #pragma unroll
    for (int k = 0; k < 16; ++k) wF[k] = 0.f;
    b0 = bhh0[h]; b1 = bhh0[32+h]; b2 = bhh0[64+h]; b3 = 0.f;
    #pragma unroll
    for (int c0 = 0; c0 < 2; ++c0)
      for (int it = 0; it < 12; ++it)
        gload16(gsrc + c0*3072 + it*256 + lane*4, &gib[c0][it*256]);
    asm volatile("s_waitcnt vmcnt(0)" ::: "memory");
  } else {
    #pragma unroll
    for (int g = 0; g < 3; ++g){
      const float* wi = wih1 + (g*32+h)*32 + ko;
      const float* wh = whh1 + (g*32+h)*32 + ko;
      #pragma unroll
      for (int k = 0; k < 16; ++k){ wI[g][k] = wi[k]; wH[g][k] = wh[k]; }
    }
    #pragma unroll
    for (int k = 0; k < 16; ++k) wF[k] = fco[(ko+k)*32 + h];
    b0 = bih1[h] + bhh1[h];
    b1 = bih1[32+h] + bhh1[32+h];
    b2 = bih1[64+h];
    b3 = bhh1[64+h];
  }
  #pragma unroll
  for (int g = 0; g < 3; ++g){
    #pragma unroll
    for (int k = 0; k < 16; ++k){ KEEP(wI[g][k]); KEEP(wH[g][k]); }
  }
  #pragma unroll
  for (int k = 0; k < 16; ++k) KEEP(wF[k]);
  __syncthreads();

  float hv[16];
  #pragma unroll
  for (int k = 0; k < 16; ++k) hv[k] = 0.f;
  float hOwn = 0.f;
  float c_r = 0.f, c_z = 0.f, c_n = 0.f, p_r = 0.f, p_z = 0.f, p_n = 0.f;

  for (int s = 0; s <= Tn; ++s){
    __syncthreads();
    if (wid == 0){
      if (s < Tn){
        const int t = s;
        if ((t & 31) == 0){
          if (t){
            int c = t >> 5;
            if (c < 7){
              for (int it = 0; it < 12; ++it)
                gload16(gsrc + (c+1)*3072 + it*256 + lane*4, &gib[(c+1)&1][it*256]);
            }
          }
          const float* gt = &gib[(t>>5)&1][(t&31)*96];
          c_r = gt[h]; c_z = gt[32+h]; c_n = gt[64+h];
        } else { c_r = p_r; c_z = p_z; c_n = p_n; }
        if ((t+1) & 31){
          const float* gn = &gib[((t+1)>>5)&1][((t+1)&31)*96];
          p_r = gn[h]; p_z = gn[32+h]; p_n = gn[64+h];
        }
        float pr, pz, pn;
        DOT16(pr, hv, wI[0]); DOT16(pz, hv, wI[1]); DOT16(pn, hv, wI[2]);
        pr += __shfl_xor(pr,32); pz += __shfl_xor(pz,32); pn += __shfl_xor(pn,32);
        float r = fsig(c_r + pr + b0);
        float z = fsig(c_z + pz + b1);
        float nn = ftanh(c_n + r*(pn + b2));
        float hn = nn + z*(hOwn - nn);
        hOwn = hn;
        h1arr[h] = hn;
        if (q == 0) y1buf[s & 1][h] = hn;
        *(float4*)&hv[0]  = *(const float4*)&h1arr[ko+0];
        *(float4*)&hv[4]  = *(const float4*)&h1arr[ko+4];
        *(float4*)&hv[8]  = *(const float4*)&h1arr[ko+8];
        *(float4*)&hv[12] = *(const float4*)&h1arr[ko+12];
      }
    } else {
      if (s >= 1){
        const int t = s - 1;
        const float* yb = y1buf[t & 1];
        float xv[16];
        *(float4*)&xv[0]  = *(const float4*)&yb[ko+0];
        *(float4*)&xv[4]  = *(const float4*)&yb[ko+4];
        *(float4*)&xv[8]  = *(const float4*)&yb[ko+8];
        *(float4*)&xv[12] = *(const float4*)&yb[ko+12];
        float ur, uz, ui, vr, vz, vh;
        DOT16(ur, xv, wI[0]); DOT16(uz, xv, wI[1]); DOT16(ui, xv, wI[2]);
        DOT16(vr, hv, wH[0]); DOT16(vz, hv, wH[1]); DOT16(vh, hv, wH[2]);
        float qr = ur + vr, qz = uz + vz;
        qr += __shfl_xor(qr,32); qz += __shfl_xor(qz,32);
        ui += __shfl_xor(ui,32); vh += __shfl_xor(vh,32);
        float r1 = fsig(qr + b0);
        float z1 = fsig(qz + b1);
        float n1 = ftanh(ui + b2 + r1*(vh + b3));
        float hn = n1 + z1*(hOwn - n1);
        hOwn = hn;
        h2arr[h] = hn;
        *(float4*)&hv[0]  = *(const float4*)&h2arr[ko+0];
        *(float4*)&hv[4]  = *(const float4*)&h2arr[ko+4];
        *(float4*)&hv[8]  = *(const float4*)&h2arr[ko+8];
        *(float4*)&hv[12] = *(const float4*)&h2arr[ko+12];
        float sf = 0.f;
        #pragma unroll
        for (int k = 0; k < 16; ++k) sf = fmaf(xv[k] + hv[k], wF[k], sf);
        sf += __shfl_xor(sf,32);
        if (q == 0) bmA[(b*Tn + t)*32 + h] = fsig(sf);
      }
    }
  }
}

// ---------- kP: fused low/high fc_in + PReLU + gi projections (unchanged, verified)
__global__ __launch_bounds__(256) void kP(const float* __restrict__ lpi,
    const float* __restrict__ bmA,
    const float* __restrict__ wlo, const float* __restrict__ plo,
    const float* __restrict__ whi, const float* __restrict__ phi,
    const float* __restrict__ wBT, const float* __restrict__ bB,
    float* __restrict__ giL, float* __restrict__ giH)
{
  __shared__ float xb[32*292];
  __shared__ float mb[32*100];
  const int tid = threadIdx.x;
  const int b = blockIdx.x >> 3;
  const int t0 = (blockIdx.x & 7)*32;
  const int bt0 = b*256 + t0;
  #pragma unroll
  for (int j = 0; j < 8; ++j){
    int idx = j*256 + tid;
    int row = idx >> 6, c4 = idx & 63;
    float4 v = *(const float4*)&lpi[(bt0 + row)*256 + c4*4];
    *(float4*)&xb[row*292 + c4*4] = v;
  }
  {
    int row = tid >> 3, c4 = tid & 7;
    float4 v = *(const float4*)&bmA[(bt0 + row)*32 + c4*4];
    *(float4*)&xb[row*292 + 256 + c4*4] = v;
  }
  __syncthreads();
  const int og = tid >> 3, btg = tid & 7;
  if (og < 16){
    float acc[4][4];
    #pragma unroll
    for (int bj = 0; bj < 4; ++bj){ acc[bj][0]=0.f; acc[bj][1]=0.f; acc[bj][2]=0.f; acc[bj][3]=0.f; }
    for (int kq = 0; kq < 40; ++kq){
      int k0_ = kq*4;
      int kk = (k0_ < 128) ? k0_ : k0_ + 128;
      float4 wv[4];
      #pragma unroll
      for (int i = 0; i < 4; ++i) wv[i] = *(const float4*)&wlo[(k0_+i)*64 + og*4];
      #pragma unroll
      for (int bj = 0; bj < 4; ++bj){
        float4 xv = *(const float4*)&xb[(btg + 8*bj)*292 + kk];
        FMA44(acc[bj], xv, wv);
      }
    }
    const float a = plo[0];
    #pragma unroll
    for (int bj = 0; bj < 4; ++bj){
      float4 m;
      m.x = acc[bj][0] >= 0.f ? acc[bj][0] : a*acc[bj][0];
      m.y = acc[bj][1] >= 0.f ? acc[bj][1] : a*acc[bj][1];
      m.z = acc[bj][2] >= 0.f ? acc[bj][2] : a*acc[bj][2];
      m.w = acc[bj][3] >= 0.f ? acc[bj][3] : a*acc[bj][3];
      *(float4*)&mb[(btg + 8*bj)*100 + og*4] = m;
    }
  } else if (og < 24){
    int o0 = (og - 16)*4;
    int g = o0 >> 4, r0 = o0 & 15;
    int xoff = 128 + g*80;
    float acc[4][4];
    #pragma unroll
    for (int bj = 0; bj < 4; ++bj){ acc[bj][0]=0.f; acc[bj][1]=0.f; acc[bj][2]=0.f; acc[bj][3]=0.f; }
    for (int kq = 0; kq < 20; ++kq){
      int k0_ = kq*4;
      float4 wv[4];
      #pragma unroll
      for (int i = 0; i < 4; ++i) wv[i] = *(const float4*)&whi[(g*80 + k0_ + i)*16 + r0];
      #pragma unroll
      for (int bj = 0; bj < 4; ++bj){
        float4 xv = *(const float4*)&xb[(btg + 8*bj)*292 + xoff + k0_];
        FMA44(acc[bj], xv, wv);
      }
    }
    const float a = phi[0];
    #pragma unroll
    for (int bj = 0; bj < 4; ++bj){
      float4 m;
      m.x = acc[bj][0] >= 0.f ? acc[bj][0] : a*acc[bj][0];
      m.y = acc[bj][1] >= 0.f ? acc[bj][1] : a*acc[bj][1];
      m.z = acc[bj][2] >= 0.f ? acc[bj][2] : a*acc[bj][2];
      m.w = acc[bj][3] >= 0.f ? acc[bj][3] : a*acc[bj][3];
      *(float4*)&mb[(btg + 8*bj)*100 + 64 + o0] = m;
    }
  }
  __syncthreads();
  for (int og2 = og; og2 < 72; og2 += 32){
    int woff, kbase, K, obase, dstride;
    float* dst;
    float4 bias;
    if (og2 < 48){
      woff = og2*128; kbase = (og2 >= 24) ? 32 : 0; K = 32;
      obase = og2*4; dst = giL; dstride = 192;
      bias = *(const float4*)&bB[obase];
    } else {
      int oh = og2 - 48;
      woff = 6144 + oh*64;
      int o0 = oh*4; int g = o0/48;
      kbase = 64 + g*16; K = 16;
      obase = o0; dst = giH; dstride = 96;
      bias = *(const float4*)&bB[192 + o0];
    }
    float acc[4][4];
    #pragma unroll
    for (int bj = 0; bj < 4; ++bj){ acc[bj][0]=0.f; acc[bj][1]=0.f; acc[bj][2]=0.f; acc[bj][3]=0.f; }
    for (int kq = 0; kq < K/4; ++kq){
      float4 wv[4];
      #pragma unroll
      for (int i = 0; i < 4; ++i) wv[i] = *(const float4*)&wBT[woff + (kq*4 + i)*4];
      #pragma unroll
      for (int bj = 0; bj < 4; ++bj){
        float4 xv = *(const float4*)&mb[(btg + 8*bj)*100 + kbase + kq*4];
        FMA44(acc[bj], xv, wv);
      }
    }
    #pragma unroll
    for (int bj = 0; bj < 4; ++bj){
      int btl = btg + 8*bj;
      float4 o;
      o.x = acc[bj][0] + bias.x; o.y = acc[bj][1] + bias.y;
      o.z = acc[bj][2] + bias.z; o.w = acc[bj][3] + bias.w;
      *(float4*)&dst[(bt0 + btl)*dstride + obase] = o;
    }
  }
}

// ---------- kR2: blocks 0..255 = low 2-layer GRU pipelined (4 waves);
// blocks 256..319 = high GRU (4 independent waves). Round-9 verified barriers.
__global__ __launch_bounds__(256,1) void kR2(const float* __restrict__ giL,
    const float* __restrict__ giH,
    const float* __restrict__ wihL, const float* __restrict__ whhL,
    const float* __restrict__ bihL, const float* __restrict__ bhhL,
    const float* __restrict__ whhH, const float* __restrict__ bhhH,
    float* __restrict__ acc, float* __restrict__ dfh)
{
  __shared__ __attribute__((aligned(16))) float smem[12544];
  const int tid = threadIdx.x;
  const int wid = tid >> 6;
  const int lane = tid & 63;
  if (blockIdx.x < 256){
    const int role = wid >> 1;
    const int g = wid & 1;
    const int q = lane >> 5, h = lane & 31, ko = q*16;
    const int b = blockIdx.x;
    float* gib   = smem + g*6144;
    float* y0buf = smem + 12288;
    float* h0arr = smem + 12416 + g*32;
    float* h1l   = smem + 12480;
    const float* gsrc = giL + b*49152 + g*96;

    float wI[3][16], wH[3][16];
    float b0, b1, b2, b3;
    if (role == 0){
      #pragma unroll
      for (int gt = 0; gt < 3; ++gt){
        const float* w = whhL + (g*96 + gt*32 + h)*32 + ko;
        #pragma unroll
        for (int k = 0; k < 16; ++k){ wI[gt][k] = w[k]; wH[gt][k] = w[k]; }
      }
      b0 = bhhL[g*96+h]; b1 = bhhL[g*96+32+h]; b2 = bhhL[g*96+64+h]; b3 = 0.f;
      #pragma unroll
      for (int c0 = 0; c0 < 2; ++c0)
        for (int it = 0; it < 12; ++it){
          int i = it*64 + lane;
          int toff = i/24, c4 = i - toff*24;
          gload16(gsrc + (c0*32 + toff)*192 + c4*4, &gib[c0*3072 + it*256]);
        }
      asm volatile("s_waitcnt vmcnt(0)" ::: "memory");
    } else {
      #pragma unroll
      for (int gt = 0; gt < 3; ++gt){
        const float* wi = wihL + ((2+g)*96 + gt*32 + h)*32 + ko;
        const float* wh = whhL + ((2+g)*96 + gt*32 + h)*32 + ko;
        #pragma unroll
        for (int k = 0; k < 16; ++k){ wI[gt][k] = wi[k]; wH[gt][k] = wh[k]; }
      }
      b0 = bihL[(2+g)*96+h]    + bhhL[(2+g)*96+h];
      b1 = bihL[(2+g)*96+32+h] + bhhL[(2+g)*96+32+h];
      b2 = bihL[(2+g)*96+64+h];
      b3 = bhhL[(2+g)*96+64+h];
    }
    #pragma unroll
    for (int gt = 0; gt < 3; ++gt){
      #pragma unroll
      for (int k = 0; k < 16; ++k){ KEEP(wI[gt][k]); KEEP(wH[gt][k]); }
    }
    __syncthreads();

    float hv[16];
    #pragma unroll
    for (int k = 0; k < 16; ++k) hv[k] = 0.f;
    float hOwn = 0.f;
    float c_r = 0.f, c_z = 0.f, c_n = 0.f, p_r = 0.f, p_z = 0.f, p_n = 0.f;
    const int spos = ((h&1)<<5) + (g<<4) + (h>>1);

    for (int s = 0; s <= Tn; ++s){
      __syncthreads();
      if (role == 0){
        if (s < Tn){
          const int t = s;
          if ((t & 31) == 0){
            if (t){
              int c = t >> 5;
              if (c < 7){
                for (int it = 0; it < 12; ++it){
                  int i = it*64 + lane;
                  int toff = i/24, c4 = i - toff*24;
                  gload16(gsrc + ((c+1)*32 + toff)*192 + c4*4, &gib[((c+1)&1)*3072 + it*256]);
                }
              }
            }
            const float* gt = &gib[((t>>5)&1)*3072 + (t&31)*96];
            c_r = gt[h]; c_z = gt[32+h]; c_n = gt[64+h];
          } else { c_r = p_r; c_z = p_z; c_n = p_n; }
          if ((t+1) & 31){
            const float* gn = &gib[(((t+1)>>5)&1)*3072 + ((t+1)&31)*96];
            p_r = gn[h]; p_z = gn[32+h]; p_n = gn[64+h];
          }
          float pr, pz, pn;
          DOT16(pr, hv, wI[0]); DOT16(pz, hv, wI[1]); DOT16(pn, hv, wI[2]);
          pr += __shfl_xor(pr,32); pz += __shfl_xor(pz,32); pn += __shfl_xor(pn,32);
          float r = fsig(c_r + pr + b0);
          float z = fsig(c_z + pz + b1);
          float nn = ftanh(c_n + r*(pn + b2));
          float hn = nn + z*(hOwn - nn);
          hOwn = hn;
          h0arr[h] = hn;
          if (q == 0) y0buf[(s&1)*64 + spos] = hn;
          *(float4*)&hv[0]  = *(const float4*)&h0arr[ko+0];
          *(float4*)&hv[4]  = *(const float4*)&h0arr[ko+4];
          *(float4*)&hv[8]  = *(const float4*)&h0arr[ko+8];
          *(float4*)&hv[12] = *(const float4*)&h0arr[ko+12];
        }
      } else {
        if (s >= 1){
          const int t = s - 1;
          const float* yb = &y0buf[(t&1)*64];
          float xv[16];
          *(float4*)&xv[0]  = *(const float4*)&yb[g*32 + ko + 0];
          *(float4*)&xv[4]  = *(const float4*)&yb[g*32 + ko + 4];
          *(float4*)&xv[8]  = *(const float4*)&yb[g*32 + ko + 8];
          *(float4*)&xv[12] = *(const float4*)&yb[g*32 + ko + 12];
          float yown = yb[g*32 + h];
          float ur, uz, ui, vr, vz, vh;
          DOT16(ur, xv, wI[0]); DOT16(uz, xv, wI[1]); DOT16(ui, xv, wI[2]);
          DOT16(vr, hv, wH[0]); DOT16(vz, hv, wH[1]); DOT16(vh, hv, wH[2]);
          float qr = ur + vr, qz = uz + vz;
          qr += __shfl_xor(qr,32); qz += __shfl_xor(qz,32);
          ui += __shfl_xor(ui,32); vh += __shfl_xor(vh,32);
          float r1 = fsig(qr + b0);
          float z1 = fsig(qz + b1);
          float n1 = ftanh(ui + b2 + r1*(vh + b3));
          float hn = n1 + z1*(hOwn - n1);
          hOwn = hn;
          h1l[g*32 + h] = hn;
          *(float4*)&hv[0]  = *(const float4*)&h1l[g*32 + ko+0];
          *(float4*)&hv[4]  = *(const float4*)&h1l[g*32 + ko+4];
          *(float4*)&hv[8]  = *(const float4*)&h1l[g*32 + ko+8];
          *(float4*)&hv[12] = *(const float4*)&h1l[g*32 + ko+12];
          if (q == 0) acc[(b*256 + t)*64 + g*32 + h] = yown + hn;
        }
      }
    }
  } else {
    // ---------- high path: 4 independent waves, chunk-16, no barriers
    const int g = lane >> 5, qh = (lane >> 4) & 1, h = lane & 15, ko = qh*8;
    const int b = (blockIdx.x - 256)*4 + wid;
    float* gib  = smem + wid*3072;
    float* harr = smem + 12288 + wid*32;
    float ah[3][8];
    #pragma unroll
    for (int gt = 0; gt < 3; ++gt){
      const float* wp = whhH + (g*48 + gt*16 + h)*16 + ko;
      #pragma unroll
      for (int k = 0; k < 8; ++k) ah[gt][k] = wp[k];
    }
    #pragma unroll
    for (int gt = 0; gt < 3; ++gt){
      #pragma unroll
      for (int k = 0; k < 8; ++k) KEEP(ah[gt][k]);
    }
    const float bhr = bhhH[g*48+h], bhz = bhhH[g*48+16+h], bhn = bhhH[g*48+32+h];
    const float* gsrc = giH + b*24576;
    #pragma unroll
    for (int c0 = 0; c0 < 2; ++c0)
      for (int it = 0; it < 6; ++it)
        gload16(gsrc + c0*1536 + it*256 + lane*4, &gib[c0*1536 + it*256]);
    asm volatile("s_waitcnt vmcnt(0)" ::: "memory");

    float hv[8];
    #pragma unroll
    for (int k = 0; k < 8; ++k) hv[k] = 0.f;
    float hOwn = 0.f;
    float c_r = 0.f, c_z = 0.f, c_n = 0.f, p_r = 0.f, p_z = 0.f, p_n = 0.f;

    for (int t = 0; t < Tn; ++t){
      if ((t & 15) == 0){
        if (t){
          int c = t >> 4;
          if (c < 15){
            const float* gs = gsrc + (c+1)*1536;
            for (int it = 0; it < 6; ++it)
              gload16(gs + it*256 + lane*4, &gib[((c+1)&1)*1536 + it*256]);
            asm volatile("s_waitcnt vmcnt(6)" ::: "memory");
          } else {
            asm volatile("s_waitcnt vmcnt(0)" ::: "memory");
          }
        }
        const float* gt = &gib[((t>>4)&1)*1536 + (t&15)*96 + g*48];
        c_r = gt[h]; c_z = gt[16+h]; c_n = gt[32+h];
      } else { c_r = p_r; c_z = p_z; c_n = p_n; }
      if ((t+1) & 15){
        const float* gn = &gib[(((t+1)>>4)&1)*1536 + ((t+1)&15)*96 + g*48];
        p_r = gn[h]; p_z = gn[16+h]; p_n = gn[32+h];
      }
      float pr, pz, pn;
      DOT8(pr, hv, ah[0]); DOT8(pz, hv, ah[1]); DOT8(pn, hv, ah[2]);
      pr += __shfl_xor(pr,16); pz += __shfl_xor(pz,16); pn += __shfl_xor(pn,16);
      float r = fsig(c_r + pr + bhr);
      float z = fsig(c_z + pz + bhz);
      float nn = ftanh(c_n + r*(pn + bhn));
      float hn = nn + z*(hOwn - nn);
      hOwn = hn;
      harr[g*16 + h] = hn;
      *(float4*)&hv[0] = *(const float4*)&harr[g*16 + ko + 0];
      *(float4*)&hv[4] = *(const float4*)&harr[g*16 + ko + 4];
      if (qh == 0) dfh[(b*256 + t)*32 + g*16 + h] = hn;
    }
  }
}

// ---------- k7: register-resident masks, PLAIN stores (A/B vs round-11 NT stores)
__global__ __launch_bounds__(256) void k7(const float* __restrict__ acc,
    const float* __restrict__ dfh, const float* __restrict__ bmA,
    const float* __restrict__ wlo, const float* __restrict__ whi,
    const float* __restrict__ spec, float* __restrict__ out)
{
  __shared__ float accs[32][65];
  __shared__ float dfhs[32][33];
  __shared__ float bmt[32][33];
  __shared__ float frcs[257];
  __shared__ int   ibds[257];
  const int tid = threadIdx.x;
  const int b  = blockIdx.x >> 3;
  const int t0 = (blockIdx.x & 7) * 32;
  for (int idx = tid; idx < 32*16; idx += 256){
    int tl = idx >> 4, c4 = (idx & 15)*4;
    float4 v = *(const float4*)&acc[(b*256 + t0 + tl)*64 + c4];
    accs[tl][c4] = v.x; accs[tl][c4+1] = v.y; accs[tl][c4+2] = v.z; accs[tl][c4+3] = v.w;
  }
  for (int idx = tid; idx < 32*8; idx += 256){
    int tl = idx >> 3, c4 = (idx & 7)*4;
    float4 v = *(const float4*)&dfh[(b*256 + t0 + tl)*32 + c4];
    dfhs[tl][c4] = v.x; dfhs[tl][c4+1] = v.y; dfhs[tl][c4+2] = v.z; dfhs[tl][c4+3] = v.w;
    float4 u = *(const float4*)&bmA[(b*Tn + t0 + tl)*32 + c4];
    bmt[tl][c4] = u.x; bmt[tl][c4+1] = u.y; bmt[tl][c4+2] = u.z; bmt[tl][c4+3] = u.w;
  }
  for (int f = tid; f < 257; f += 256){
    int i = 0;
    #pragma unroll
    for (int k = 1; k < 31; ++k) if (f >= EB[k]) i = k;
    ibds[f] = i;
    frcs[f] = (f < 256) ? (float)(f - EB[i]) / (float)(EB[i+1] - EB[i]) : 0.f;
  }
  __syncthreads();
  const int tl = tid & 31, fo = tid >> 5;
  float* out1 = out + 16842752;
  float* out2 = out + 2*16842752;
  float* out3 = out + 3*16842752;
  const float2* sp2 = (const float2*)spec;
  {
    float p[16];
    #pragma unroll
    for (int j = 0; j < 16; ++j) p[j] = 0.f;
    for (int i = 0; i < 64; ++i){
      float a = accs[tl][i];
      const float4* wr = (const float4*)&wlo[i*128 + fo*16];
      #pragma unroll
      for (int j4 = 0; j4 < 4; ++j4){
        float4 wv = wr[j4];
        p[j4*4+0] = fmaf(a, wv.x, p[j4*4+0]);
        p[j4*4+1] = fmaf(a, wv.y, p[j4*4+1]);
        p[j4*4+2] = fmaf(a, wv.z, p[j4*4+2]);
        p[j4*4+3] = fmaf(a, wv.w, p[j4*4+3]);
      }
    }
    #pragma unroll
    for (int j = 0; j < 16; ++j){
      int f = fo*16 + j;
      int i = ibds[f]; float fr = frcs[f];
      float full = bmt[tl][i]*(1.f - fr) + bmt[tl][i+1]*fr;
      float m = fsig(p[j])*full;
      int base = (b*257 + f)*Tn + t0 + tl;
      float2 s = sp2[base];
      float fm = full*m;
      float sx = s.x*fm, sy = s.y*fm;
      out[base]  = full;
      out1[base] = m;
      out2[base] = sqrtf(sx*sx + sy*sy);
      *(v2f*)&out3[base*2] = (v2f){sx, sy};
    }
  }
  {
    float p[16];
    #pragma unroll
    for (int j = 0; j < 16; ++j) p[j] = 0.f;
    const int g = fo >> 2, ob = (fo & 3)*16;
    for (int i = 0; i < 16; ++i){
      float a = dfhs[tl][g*16 + i];
      const float4* wr = (const float4*)&whi[(g*16 + i)*64 + ob];
      #pragma unroll
      for (int j4 = 0; j4 < 4; ++j4){
        float4 wv = wr[j4];
        p[j4*4+0] = fmaf(a, wv.x, p[j4*4+0]);
        p[j4*4+1] = fmaf(a, wv.y, p[j4*4+1]);
        p[j4*4+2] = fmaf(a, wv.z, p[j4*4+2]);
        p[j4*4+3] = fmaf(a, wv.w, p[j4*4+3]);
      }
    }
    #pragma unroll
    for (int j = 0; j < 16; ++j){
      int f = 128 + fo*16 + j;
      int i = ibds[f]; float fr = frcs[f];
      float full = bmt[tl][i]*(1.f - fr) + bmt[tl][i+1]*fr;
      float m = fsig(p[j])*full;
      int base = (b*257 + f)*Tn + t0 + tl;
      float2 s = sp2[base];
      float fm = full*m;
      float sx = s.x*fm, sy = s.y*fm;
      out[base]  = full;
      out1[base] = m;
      out2[base] = sqrtf(sx*sx + sy*sy);
      *(v2f*)&out3[base*2] = (v2f){sx, sy};
    }
  }
  if (fo == 0){
    int base = (b*257 + 256)*Tn + t0 + tl;
    out[base]  = 0.f;
    out1[base] = 0.f;
    out2[base] = 0.f;
    *(v2f*)&out3[base*2] = (v2f){0.f, 0.f};
  }
}

extern "C" void kernel_launch(void* const* d_in, const int* in_sizes, int n_in,
                              void* d_out, int out_size, void* d_ws, size_t ws_size,
                              hipStream_t stream){
  const float* mi   = (const float*)d_in[0];
  const float* spec = (const float*)d_in[1];
  const float* lpi  = (const float*)d_in[2];
  const float* s1w  = (const float*)d_in[5];
  const float* s1b  = (const float*)d_in[6];
  const float* wih0 = (const float*)d_in[7];
  const float* whh0 = (const float*)d_in[8];
  const float* bih0 = (const float*)d_in[9];
  const float* bhh0 = (const float*)d_in[10];
  const float* wih1 = (const float*)d_in[11];
  const float* whh1 = (const float*)d_in[12];
  const float* bih1 = (const float*)d_in[13];
  const float* bhh1 = (const float*)d_in[14];
  const float* fco  = (const float*)d_in[15];
  const float* filw = (const float*)d_in[16];
  const float* plo  = (const float*)d_in[17];
  const float* fihw = (const float*)d_in[18];
  const float* phi  = (const float*)d_in[19];
  const float* glw_ih = (const float*)d_in[20];
  const float* glw_hh = (const float*)d_in[21];
  const float* glb_ih = (const float*)d_in[22];
  const float* glb_hh = (const float*)d_in[23];
  const float* ghw_ih = (const float*)d_in[24];
  const float* ghw_hh = (const float*)d_in[25];
  const float* ghb_ih = (const float*)d_in[26];
  const float* ghb_hh = (const float*)d_in[27];
  const float* folw = (const float*)d_in[28];
  const float* fohw = (const float*)d_in[29];

  // big gi scratch lives in d_out (fully overwritten by k7 at the end)
  float* outf = (float*)d_out;
  float* giL  = outf;                     // [b][t][192] 12,582,912
  float* gi0  = outf + 12582912;          // [b][t][96]   6,291,456
  float* giH  = outf + 18874368;          // [b][t][96]   6,291,456

  float* ws  = (float*)d_ws;
  float* wcT = ws;                        // 6144
  float* bc  = ws + 6144;                 // 96
  float* wBT = ws + 6240;                 // 7680
  float* bB  = ws + 13920;                // 288
  float* bmA = ws + 14336;                // [b][t][32]  2,097,152
  float* acc = ws + 2111488;              // [b][t][64]  4,194,304
  float* dfh = ws + 6305792;              // [b][t][32]  2,097,152
  float* out = (float*)d_out;

  k0<<<56, 256, 0, stream>>>(s1w, s1b, wih0, bih0, glw_ih, glb_ih, ghw_ih, ghb_ih,
                             wcT, bc, wBT, bB);
  k1<<<2048, 256, 0, stream>>>(mi, wcT, bc, gi0);
  kS1<<<256, 128, 0, stream>>>(gi0, whh0, bhh0, wih1, whh1, bih1, bhh1, fco, bmA);
  kP<<<2048, 256, 0, stream>>>(lpi, bmA, filw, plo, fihw, phi, wBT, bB, giL, giH);
  kR2<<<320, 256, 0, stream>>>(giL, giH, glw_ih, glw_hh, glb_ih, glb_hh,
                               ghw_hh, ghb_hh, acc, dfh);
  k7<<<2048, 256, 0, stream>>>(acc, dfh, bmA, folw, fohw, spec, out);
}

// Round 13
// 483.331 us; speedup vs baseline: 1.3098x; 1.2084x over previous
//
#include <hip/hip_runtime.h>
#include <math.h>

#define Bn 256
#define Tn 256

__constant__ int EB[32] = {0,3,5,8,10,13,15,18,22,25,29,33,38,42,48,53,59,66,73,80,89,97,107,117,128,140,153,167,183,199,216,256};

__device__ __forceinline__ float fsig(float x){ return __builtin_amdgcn_rcpf(1.f + __expf(-x)); }
__device__ __forceinline__ float ftanh(float x){ return 1.f - 2.f*__builtin_amdgcn_rcpf(1.f + __expf(2.f*x)); }

__device__ __forceinline__ void gload16(const float* g, float* l){
  __builtin_amdgcn_global_load_lds((const __attribute__((address_space(1))) void*)g,
                                   (__attribute__((address_space(3))) void*)l, 16, 0, 0);
}

#define KEEP(x) asm volatile("" : "+v"(x))

#define DOT16(res, X, W) do{ float _s0=0.f,_s1=0.f,_s2=0.f,_s3=0.f; \
  _Pragma("unroll") for (int _e=0;_e<4;++_e){ \
    _s0=fmaf((X)[_e],(W)[_e],_s0); _s1=fmaf((X)[4+_e],(W)[4+_e],_s1); \
    _s2=fmaf((X)[8+_e],(W)[8+_e],_s2); _s3=fmaf((X)[12+_e],(W)[12+_e],_s3);} \
  (res)=(_s0+_s1)+(_s2+_s3); }while(0)

#define DOT8(res, X, W) do{ float _s0=0.f,_s1=0.f; \
  _Pragma("unroll") for (int _e=0;_e<4;++_e){ \
    _s0=fmaf((X)[_e],(W)[_e],_s0); _s1=fmaf((X)[4+_e],(W)[4+_e],_s1);} \
  (res)=_s0+_s1; }while(0)

#define FMA44(A, X, W) do{ \
  (A)[0]=fmaf((X).x,(W)[0].x,(A)[0]); (A)[1]=fmaf((X).x,(W)[0].y,(A)[1]); (A)[2]=fmaf((X).x,(W)[0].z,(A)[2]); (A)[3]=fmaf((X).x,(W)[0].w,(A)[3]); \
  (A)[0]=fmaf((X).y,(W)[1].x,(A)[0]); (A)[1]=fmaf((X).y,(W)[1].y,(A)[1]); (A)[2]=fmaf((X).y,(W)[1].z,(A)[2]); (A)[3]=fmaf((X).y,(W)[1].w,(A)[3]); \
  (A)[0]=fmaf((X).z,(W)[2].x,(A)[0]); (A)[1]=fmaf((X).z,(W)[2].y,(A)[1]); (A)[2]=fmaf((X).z,(W)[2].z,(A)[2]); (A)[3]=fmaf((X).z,(W)[2].w,(A)[3]); \
  (A)[0]=fmaf((X).w,(W)[3].x,(A)[0]); (A)[1]=fmaf((X).w,(W)[3].y,(A)[1]); (A)[2]=fmaf((X).w,(W)[3].z,(A)[2]); (A)[3]=fmaf((X).w,(W)[3].w,(A)[3]); \
}while(0)

// p (float4 over t) += av * scalar
#define FMA4V(P, AV, S) do{ (P).x=fmaf((AV).x,(S),(P).x); (P).y=fmaf((AV).y,(S),(P).y); \
  (P).z=fmaf((AV).z,(S),(P).z); (P).w=fmaf((AV).w,(S),(P).w); }while(0)

// ---------- k0: weight prep (unchanged, verified)
__global__ __launch_bounds__(256) void k0(const float* __restrict__ wfc, const float* __restrict__ bfc,
    const float* __restrict__ wih0, const float* __restrict__ bih0,
    const float* __restrict__ glw_ih, const float* __restrict__ glb_ih,
    const float* __restrict__ ghw_ih, const float* __restrict__ ghb_ih,
    float* __restrict__ wcT, float* __restrict__ bc,
    float* __restrict__ wBT, float* __restrict__ bB){
  int i = blockIdx.x*256 + threadIdx.x;
  if (i < 6144){
    int k = i/96, o = i - (i/96)*96;
    float s = 0.f;
    #pragma unroll
    for (int kk = 0; kk < 32; ++kk) s = fmaf(wih0[o*32+kk], wfc[kk*64+k], s);
    wcT[i] = s;
  } else if (i < 6240){
    int o = i - 6144;
    float s = bih0[o];
    #pragma unroll
    for (int kk = 0; kk < 32; ++kk) s = fmaf(wih0[o*32+kk], bfc[kk], s);
    bc[o] = s;
  } else if (i < 13920){
    int j = i - 6240;
    if (j < 6144){
      int og = j >> 7, rem = j & 127, k = rem >> 2, jj = rem & 3;
      int o = og*4 + jj; int g = o/96, r = o - g*96;
      wBT[j] = glw_ih[(g*96 + r)*32 + k];
    } else {
      int j2 = j - 6144;
      int oh = j2 >> 6, rem = j2 & 63, k = rem >> 2, jj = rem & 3;
      int o = oh*4 + jj; int g = o/48, r = o - g*48;
      wBT[j] = ghw_ih[(g*48 + r)*16 + k];
    }
  } else if (i < 14208){
    int o = i - 13920;
    bB[o] = (o < 192) ? glb_ih[o] : ghb_ih[o - 192];
  }
}

// ---------- k1: gi0[b][t][96] (unchanged, verified)
__global__ __launch_bounds__(256) void k1(const float* __restrict__ mi,
    const float* __restrict__ wcT, const float* __restrict__ bc,
    float* __restrict__ gi0){
  __shared__ float mbuf[33*36];
  const int tid = threadIdx.x;
  const int b = blockIdx.x >> 3;
  const int t0 = (blockIdx.x & 7)*32;
  const int bt0 = b*256 + t0;
  for (int idx = tid; idx < 264; idx += 256){
    int row = idx >> 3, c4 = idx & 7;
    int r = t0 - 1 + row;
    float4 v = make_float4(0.f,0.f,0.f,0.f);
    if (r >= 0) v = *(const float4*)&mi[(b*256 + r)*32 + c4*4];
    *(float4*)&mbuf[row*36 + c4*4] = v;
  }
  __syncthreads();
  const int og = tid >> 3, btg = tid & 7;
  if (og >= 24) return;
  float acc[4][4];
  #pragma unroll
  for (int bj = 0; bj < 4; ++bj){ acc[bj][0]=0.f; acc[bj][1]=0.f; acc[bj][2]=0.f; acc[bj][3]=0.f; }
  for (int fq = 0; fq < 8; ++fq){
    float4 wvp[4], wvc[4];
    #pragma unroll
    for (int i = 0; i < 4; ++i){
      int f = fq*4 + i;
      wvp[i] = *(const float4*)&wcT[(2*f)*96 + og*4];
      wvc[i] = *(const float4*)&wcT[(2*f+1)*96 + og*4];
    }
    #pragma unroll
    for (int bj = 0; bj < 4; ++bj){
      int btl = btg + 8*bj;
      float4 xp = *(const float4*)&mbuf[btl*36 + fq*4];
      float4 xc = *(const float4*)&mbuf[(btl+1)*36 + fq*4];
      FMA44(acc[bj], xp, wvp);
      FMA44(acc[bj], xc, wvc);
    }
  }
  float4 bias = *(const float4*)&bc[og*4];
  #pragma unroll
  for (int bj = 0; bj < 4; ++bj){
    int btl = btg + 8*bj;
    float4 o;
    o.x = acc[bj][0] + bias.x; o.y = acc[bj][1] + bias.y;
    o.z = acc[bj][2] + bias.z; o.w = acc[bj][3] + bias.w;
    *(float4*)&gi0[(bt0 + btl)*96 + og*4] = o;
  }
}

// ---------- kSP: blocks 0..255 = kS1 (stage1 pipelined double GRU, round-9 verified);
// blocks 256..2303 = kPa (bmA-independent partial fc_in sums -> pmid), rides concurrently.
__global__ __launch_bounds__(128,1) void kSP(const float* __restrict__ gi0,
    const float* __restrict__ whh0, const float* __restrict__ bhh0,
    const float* __restrict__ wih1, const float* __restrict__ whh1,
    const float* __restrict__ bih1, const float* __restrict__ bhh1,
    const float* __restrict__ fco, float* __restrict__ bmA,
    const float* __restrict__ lpi,
    const float* __restrict__ wlo, const float* __restrict__ whi,
    float* __restrict__ pmid)
{
  __shared__ __attribute__((aligned(16))) float smem[8320];
  const int tid = threadIdx.x;
  if (blockIdx.x < 256){
    // ====== kS1 body (verified) ======
    float* gib   = smem;            // [2][3072]
    float* y1buf = smem + 6144;     // [2][32]
    float* h1arr = smem + 6208;
    float* h2arr = smem + 6240;
    const int wid = tid >> 6;
    const int lane = tid & 63;
    const int q = lane >> 5, h = lane & 31, ko = q*16;
    const int b = blockIdx.x;
    const float* gsrc = gi0 + b*24576;

    float wI[3][16], wH[3][16], wF[16];
    float b0, b1, b2, b3;
    if (wid == 0){
      #pragma unroll
      for (int g = 0; g < 3; ++g){
        const float* w = whh0 + (g*32+h)*32 + ko;
        #pragma unroll
        for (int k = 0; k < 16; ++k){ wI[g][k] = w[k]; wH[g][k] = w[k]; }
      }
      #pragma unroll
      for (int k = 0; k < 16; ++k) wF[k] = 0.f;
      b0 = bhh0[h]; b1 = bhh0[32+h]; b2 = bhh0[64+h]; b3 = 0.f;
      #pragma unroll
      for (int c0 = 0; c0 < 2; ++c0)
        for (int it = 0; it < 12; ++it)
          gload16(gsrc + c0*3072 + it*256 + lane*4, &gib[c0*3072 + it*256]);
      asm volatile("s_waitcnt vmcnt(0)" ::: "memory");
    } else {
      #pragma unroll
      for (int g = 0; g < 3; ++g){
        const float* wi = wih1 + (g*32+h)*32 + ko;
        const float* wh = whh1 + (g*32+h)*32 + ko;
        #pragma unroll
        for (int k = 0; k < 16; ++k){ wI[g][k] = wi[k]; wH[g][k] = wh[k]; }
      }
      #pragma unroll
      for (int k = 0; k < 16; ++k) wF[k] = fco[(ko+k)*32 + h];
      b0 = bih1[h] + bhh1[h];
      b1 = bih1[32+h] + bhh1[32+h];
      b2 = bih1[64+h];
      b3 = bhh1[64+h];
    }
    #pragma unroll
    for (int g = 0; g < 3; ++g){
      #pragma unroll
      for (int k = 0; k < 16; ++k){ KEEP(wI[g][k]); KEEP(wH[g][k]); }
    }
    #pragma unroll
    for (int k = 0; k < 16; ++k) KEEP(wF[k]);
    __syncthreads();

    float hv[16];
    #pragma unroll
    for (int k = 0; k < 16; ++k) hv[k] = 0.f;
    float hOwn = 0.f;
    float c_r = 0.f, c_z = 0.f, c_n = 0.f, p_r = 0.f, p_z = 0.f, p_n = 0.f;

    for (int s = 0; s <= Tn; ++s){
      __syncthreads();
      if (wid == 0){
        if (s < Tn){
          const int t = s;
          if ((t & 31) == 0){
            if (t){
              int c = t >> 5;
              if (c < 7){
                for (int it = 0; it < 12; ++it)
                  gload16(gsrc + (c+1)*3072 + it*256 + lane*4, &gib[((c+1)&1)*3072 + it*256]);
              }
            }
            const float* gt = &gib[((t>>5)&1)*3072 + (t&31)*96];
            c_r = gt[h]; c_z = gt[32+h]; c_n = gt[64+h];
          } else { c_r = p_r; c_z = p_z; c_n = p_n; }
          if ((t+1) & 31){
            const float* gn = &gib[(((t+1)>>5)&1)*3072 + ((t+1)&31)*96];
            p_r = gn[h]; p_z = gn[32+h]; p_n = gn[64+h];
          }
          float pr, pz, pn;
          DOT16(pr, hv, wI[0]); DOT16(pz, hv, wI[1]); DOT16(pn, hv, wI[2]);
          pr += __shfl_xor(pr,32); pz += __shfl_xor(pz,32); pn += __shfl_xor(pn,32);
          float r = fsig(c_r + pr + b0);
          float z = fsig(c_z + pz + b1);
          float nn = ftanh(c_n + r*(pn + b2));
          float hn = nn + z*(hOwn - nn);
          hOwn = hn;
          h1arr[h] = hn;
          if (q == 0) y1buf[(s & 1)*32 + h] = hn;
          *(float4*)&hv[0]  = *(const float4*)&h1arr[ko+0];
          *(float4*)&hv[4]  = *(const float4*)&h1arr[ko+4];
          *(float4*)&hv[8]  = *(const float4*)&h1arr[ko+8];
          *(float4*)&hv[12] = *(const float4*)&h1arr[ko+12];
        }
      } else {
        if (s >= 1){
          const int t = s - 1;
          const float* yb = &y1buf[(t & 1)*32];
          float xv[16];
          *(float4*)&xv[0]  = *(const float4*)&yb[ko+0];
          *(float4*)&xv[4]  = *(const float4*)&yb[ko+4];
          *(float4*)&xv[8]  = *(const float4*)&yb[ko+8];
          *(float4*)&xv[12] = *(const float4*)&yb[ko+12];
          float ur, uz, ui, vr, vz, vh;
          DOT16(ur, xv, wI[0]); DOT16(uz, xv, wI[1]); DOT16(ui, xv, wI[2]);
          DOT16(vr, hv, wH[0]); DOT16(vz, hv, wH[1]); DOT16(vh, hv, wH[2]);
          float qr = ur + vr, qz = uz + vz;
          qr += __shfl_xor(qr,32); qz += __shfl_xor(qz,32);
          ui += __shfl_xor(ui,32); vh += __shfl_xor(vh,32);
          float r1 = fsig(qr + b0);
          float z1 = fsig(qz + b1);
          float n1 = ftanh(ui + b2 + r1*(vh + b3));
          float hn = n1 + z1*(hOwn - n1);
          hOwn = hn;
          h2arr[h] = hn;
          *(float4*)&hv[0]  = *(const float4*)&h2arr[ko+0];
          *(float4*)&hv[4]  = *(const float4*)&h2arr[ko+4];
          *(float4*)&hv[8]  = *(const float4*)&h2arr[ko+8];
          *(float4*)&hv[12] = *(const float4*)&h2arr[ko+12];
          float sf = 0.f;
          #pragma unroll
          for (int k = 0; k < 16; ++k) sf = fmaf(xv[k] + hv[k], wF[k], sf);
          sf += __shfl_xor(sf,32);
          if (q == 0) bmA[(b*Tn + t)*32 + h] = fsig(sf);
        }
      }
    }
  } else {
    // ====== kPa: partial fc_in sums over lpi-only K ======
    float* xb = smem;               // [32][260]
    const int blk = blockIdx.x - 256;
    const int b = blk >> 3;
    const int t0 = (blk & 7)*32;
    const int bt0 = b*256 + t0;
    #pragma unroll
    for (int j = 0; j < 16; ++j){
      int idx = j*128 + tid;
      int row = idx >> 6, c4 = idx & 63;
      float4 v = *(const float4*)&lpi[(bt0 + row)*256 + c4*4];
      *(float4*)&xb[row*260 + c4*4] = v;
    }
    __syncthreads();
    const int og = tid >> 3, btg = tid & 7;
    for (int og2 = og; og2 < 24; og2 += 16){
      float acc[4][4];
      #pragma unroll
      for (int bj = 0; bj < 4; ++bj){ acc[bj][0]=0.f; acc[bj][1]=0.f; acc[bj][2]=0.f; acc[bj][3]=0.f; }
      int obase;
      if (og2 < 16){
        for (int kq = 0; kq < 32; ++kq){
          int k0_ = kq*4;
          float4 wv[4];
          #pragma unroll
          for (int i = 0; i < 4; ++i) wv[i] = *(const float4*)&wlo[(k0_+i)*64 + og2*4];
          #pragma unroll
          for (int bj = 0; bj < 4; ++bj){
            float4 xv = *(const float4*)&xb[(btg + 8*bj)*260 + k0_];
            FMA44(acc[bj], xv, wv);
          }
        }
        obase = og2*4;
      } else {
        int o0 = (og2 - 16)*4;
        int g = o0 >> 4, r0 = o0 & 15;
        int xoff = 128 + g*80;
        int nk = (g == 0) ? 20 : 12;
        for (int kq = 0; kq < nk; ++kq){
          int k0_ = kq*4;
          float4 wv[4];
          #pragma unroll
          for (int i = 0; i < 4; ++i) wv[i] = *(const float4*)&whi[(g*80 + k0_ + i)*16 + r0];
          #pragma unroll
          for (int bj = 0; bj < 4; ++bj){
            float4 xv = *(const float4*)&xb[(btg + 8*bj)*260 + xoff + k0_];
            FMA44(acc[bj], xv, wv);
          }
        }
        obase = 64 + o0;
      }
      #pragma unroll
      for (int bj = 0; bj < 4; ++bj){
        int btl = btg + 8*bj;
        float4 o;
        o.x = acc[bj][0]; o.y = acc[bj][1]; o.z = acc[bj][2]; o.w = acc[bj][3];
        *(float4*)&pmid[(bt0 + btl)*96 + obase] = o;
      }
    }
  }
}

// ---------- kPb: bm-tail of fc_in + PReLU + gi projections
__global__ __launch_bounds__(256) void kPb(const float* __restrict__ bmA,
    const float* __restrict__ pmid,
    const float* __restrict__ wlo, const float* __restrict__ plo,
    const float* __restrict__ whi, const float* __restrict__ phi,
    const float* __restrict__ wBT, const float* __restrict__ bB,
    float* __restrict__ giL, float* __restrict__ giH)
{
  __shared__ float bmb[32*36];
  __shared__ float mb[32*100];
  const int tid = threadIdx.x;
  const int b = blockIdx.x >> 3;
  const int t0 = (blockIdx.x & 7)*32;
  const int bt0 = b*256 + t0;
  {
    int row = tid >> 3, c4 = tid & 7;
    float4 v = *(const float4*)&bmA[(bt0 + row)*32 + c4*4];
    *(float4*)&bmb[row*36 + c4*4] = v;
  }
  __syncthreads();
  const int og = tid >> 3, btg = tid & 7;
  if (og < 16){
    float acc[4][4];
    #pragma unroll
    for (int bj = 0; bj < 4; ++bj){
      float4 p = *(const float4*)&pmid[(bt0 + btg + 8*bj)*96 + og*4];
      acc[bj][0] = p.x; acc[bj][1] = p.y; acc[bj][2] = p.z; acc[bj][3] = p.w;
    }
    for (int kq = 0; kq < 8; ++kq){
      int k0_ = kq*4;
      float4 wv[4];
      #pragma unroll
      for (int i = 0; i < 4; ++i) wv[i] = *(const float4*)&wlo[(128 + k0_ + i)*64 + og*4];
      #pragma unroll
      for (int bj = 0; bj < 4; ++bj){
        float4 xv = *(const float4*)&bmb[(btg + 8*bj)*36 + k0_];
        FMA44(acc[bj], xv, wv);
      }
    }
    const float a = plo[0];
    #pragma unroll
    for (int bj = 0; bj < 4; ++bj){
      float4 m;
      m.x = acc[bj][0] >= 0.f ? acc[bj][0] : a*acc[bj][0];
      m.y = acc[bj][1] >= 0.f ? acc[bj][1] : a*acc[bj][1];
      m.z = acc[bj][2] >= 0.f ? acc[bj][2] : a*acc[bj][2];
      m.w = acc[bj][3] >= 0.f ? acc[bj][3] : a*acc[bj][3];
      *(float4*)&mb[(btg + 8*bj)*100 + og*4] = m;
    }
  } else if (og < 24){
    int o0 = (og - 16)*4;
    int g = o0 >> 4, r0 = o0 & 15;
    float acc[4][4];
    #pragma unroll
    for (int bj = 0; bj < 4; ++bj){
      float4 p = *(const float4*)&pmid[(bt0 + btg + 8*bj)*96 + 64 + o0];
      acc[bj][0] = p.x; acc[bj][1] = p.y; acc[bj][2] = p.z; acc[bj][3] = p.w;
    }
    if (g == 1){
      for (int kq = 0; kq < 8; ++kq){
        int k0_ = 48 + kq*4;
        float4 wv[4];
        #pragma unroll
        for (int i = 0; i < 4; ++i) wv[i] = *(const float4*)&whi[(80 + k0_ + i)*16 + r0];
        #pragma unroll
        for (int bj = 0; bj < 4; ++bj){
          float4 xv = *(const float4*)&bmb[(btg + 8*bj)*36 + kq*4];
          FMA44(acc[bj], xv, wv);
        }
      }
    }
    const float a = phi[0];
    #pragma unroll
    for (int bj = 0; bj < 4; ++bj){
      float4 m;
      m.x = acc[bj][0] >= 0.f ? acc[bj][0] : a*acc[bj][0];
      m.y = acc[bj][1] >= 0.f ? acc[bj][1] : a*acc[bj][1];
      m.z = acc[bj][2] >= 0.f ? acc[bj][2] : a*acc[bj][2];
      m.w = acc[bj][3] >= 0.f ? acc[bj][3] : a*acc[bj][3];
      *(float4*)&mb[(btg + 8*bj)*100 + 64 + o0] = m;
    }
  }
  __syncthreads();
  for (int og2 = og; og2 < 72; og2 += 32){
    int woff, kbase, K, obase, dstride;
    float* dst;
    float4 bias;
    if (og2 < 48){
      woff = og2*128; kbase = (og2 >= 24) ? 32 : 0; K = 32;
      obase = og2*4; dst = giL; dstride = 192;
      bias = *(const float4*)&bB[obase];
    } else {
      int oh = og2 - 48;
      woff = 6144 + oh*64;
      int o0 = oh*4; int g = o0/48;
      kbase = 64 + g*16; K = 16;
      obase = o0; dst = giH; dstride = 96;
      bias = *(const float4*)&bB[192 + o0];
    }
    float acc[4][4];
    #pragma unroll
    for (int bj = 0; bj < 4; ++bj){ acc[bj][0]=0.f; acc[bj][1]=0.f; acc[bj][2]=0.f; acc[bj][3]=0.f; }
    for (int kq = 0; kq < K/4; ++kq){
      float4 wv[4];
      #pragma unroll
      for (int i = 0; i < 4; ++i) wv[i] = *(const float4*)&wBT[woff + (kq*4 + i)*4];
      #pragma unroll
      for (int bj = 0; bj < 4; ++bj){
        float4 xv = *(const float4*)&mb[(btg + 8*bj)*100 + kbase + kq*4];
        FMA44(acc[bj], xv, wv);
      }
    }
    #pragma unroll
    for (int bj = 0; bj < 4; ++bj){
      int btl = btg + 8*bj;
      float4 o;
      o.x = acc[bj][0] + bias.x; o.y = acc[bj][1] + bias.y;
      o.z = acc[bj][2] + bias.z; o.w = acc[bj][3] + bias.w;
      *(float4*)&dst[(bt0 + btl)*dstride + obase] = o;
    }
  }
}

// ---------- kR2: unchanged (round-12 verified)
__global__ __launch_bounds__(256,1) void kR2(const float* __restrict__ giL,
    const float* __restrict__ giH,
    const float* __restrict__ wihL, const float* __restrict__ whhL,
    const float* __restrict__ bihL, const float* __restrict__ bhhL,
    const float* __restrict__ whhH, const float* __restrict__ bhhH,
    float* __restrict__ acc, float* __restrict__ dfh)
{
  __shared__ __attribute__((aligned(16))) float smem[12544];
  const int tid = threadIdx.x;
  const int wid = tid >> 6;
  const int lane = tid & 63;
  if (blockIdx.x < 256){
    const int role = wid >> 1;
    const int g = wid & 1;
    const int q = lane >> 5, h = lane & 31, ko = q*16;
    const int b = blockIdx.x;
    float* gib   = smem + g*6144;
    float* y0buf = smem + 12288;
    float* h0arr = smem + 12416 + g*32;
    float* h1l   = smem + 12480;
    const float* gsrc = giL + b*49152 + g*96;

    float wI[3][16], wH[3][16];
    float b0, b1, b2, b3;
    if (role == 0){
      #pragma unroll
      for (int gt = 0; gt < 3; ++gt){
        const float* w = whhL + (g*96 + gt*32 + h)*32 + ko;
        #pragma unroll
        for (int k = 0; k < 16; ++k){ wI[gt][k] = w[k]; wH[gt][k] = w[k]; }
      }
      b0 = bhhL[g*96+h]; b1 = bhhL[g*96+32+h]; b2 = bhhL[g*96+64+h]; b3 = 0.f;
      #pragma unroll
      for (int c0 = 0; c0 < 2; ++c0)
        for (int it = 0; it < 12; ++it){
          int i = it*64 + lane;
          int toff = i/24, c4 = i - toff*24;
          gload16(gsrc + (c0*32 + toff)*192 + c4*4, &gib[c0*3072 + it*256]);
        }
      asm volatile("s_waitcnt vmcnt(0)" ::: "memory");
    } else {
      #pragma unroll
      for (int gt = 0; gt < 3; ++gt){
        const float* wi = wihL + ((2+g)*96 + gt*32 + h)*32 + ko;
        const float* wh = whhL + ((2+g)*96 + gt*32 + h)*32 + ko;
        #pragma unroll
        for (int k = 0; k < 16; ++k){ wI[gt][k] = wi[k]; wH[gt][k] = wh[k]; }
      }
      b0 = bihL[(2+g)*96+h]    + bhhL[(2+g)*96+h];
      b1 = bihL[(2+g)*96+32+h] + bhhL[(2+g)*96+32+h];
      b2 = bihL[(2+g)*96+64+h];
      b3 = bhhL[(2+g)*96+64+h];
    }
    #pragma unroll
    for (int gt = 0; gt < 3; ++gt){
      #pragma unroll
      for (int k = 0; k < 16; ++k){ KEEP(wI[gt][k]); KEEP(wH[gt][k]); }
    }
    __syncthreads();

    float hv[16];
    #pragma unroll
    for (int k = 0; k < 16; ++k) hv[k] = 0.f;
    float hOwn = 0.f;
    float c_r = 0.f, c_z = 0.f, c_n = 0.f, p_r = 0.f, p_z = 0.f, p_n = 0.f;
    const int spos = ((h&1)<<5) + (g<<4) + (h>>1);

    for (int s = 0; s <= Tn; ++s){
      __syncthreads();
      if (role == 0){
        if (s < Tn){
          const int t = s;
          if ((t & 31) == 0){
            if (t){
              int c = t >> 5;
              if (c < 7){
                for (int it = 0; it < 12; ++it){
                  int i = it*64 + lane;
                  int toff = i/24, c4 = i - toff*24;
                  gload16(gsrc + ((c+1)*32 + toff)*192 + c4*4, &gib[((c+1)&1)*3072 + it*256]);
                }
              }
            }
            const float* gt = &gib[((t>>5)&1)*3072 + (t&31)*96];
            c_r = gt[h]; c_z = gt[32+h]; c_n = gt[64+h];
          } else { c_r = p_r; c_z = p_z; c_n = p_n; }
          if ((t+1) & 31){
            const float* gn = &gib[(((t+1)>>5)&1)*3072 + ((t+1)&31)*96];
            p_r = gn[h]; p_z = gn[32+h]; p_n = gn[64+h];
          }
          float pr, pz, pn;
          DOT16(pr, hv, wI[0]); DOT16(pz, hv, wI[1]); DOT16(pn, hv, wI[2]);
          pr += __shfl_xor(pr,32); pz += __shfl_xor(pz,32); pn += __shfl_xor(pn,32);
          float r = fsig(c_r + pr + b0);
          float z = fsig(c_z + pz + b1);
          float nn = ftanh(c_n + r*(pn + b2));
          float hn = nn + z*(hOwn - nn);
          hOwn = hn;
          h0arr[h] = hn;
          if (q == 0) y0buf[(s&1)*64 + spos] = hn;
          *(float4*)&hv[0]  = *(const float4*)&h0arr[ko+0];
          *(float4*)&hv[4]  = *(const float4*)&h0arr[ko+4];
          *(float4*)&hv[8]  = *(const float4*)&h0arr[ko+8];
          *(float4*)&hv[12] = *(const float4*)&h0arr[ko+12];
        }
      } else {
        if (s >= 1){
          const int t = s - 1;
          const float* yb = &y0buf[(t&1)*64];
          float xv[16];
          *(float4*)&xv[0]  = *(const float4*)&yb[g*32 + ko + 0];
          *(float4*)&xv[4]  = *(const float4*)&yb[g*32 + ko + 4];
          *(float4*)&xv[8]  = *(const float4*)&yb[g*32 + ko + 8];
          *(float4*)&xv[12] = *(const float4*)&yb[g*32 + ko + 12];
          float yown = yb[g*32 + h];
          float ur, uz, ui, vr, vz, vh;
          DOT16(ur, xv, wI[0]); DOT16(uz, xv, wI[1]); DOT16(ui, xv, wI[2]);
          DOT16(vr, hv, wH[0]); DOT16(vz, hv, wH[1]); DOT16(vh, hv, wH[2]);
          float qr = ur + vr, qz = uz + vz;
          qr += __shfl_xor(qr,32); qz += __shfl_xor(qz,32);
          ui += __shfl_xor(ui,32); vh += __shfl_xor(vh,32);
          float r1 = fsig(qr + b0);
          float z1 = fsig(qz + b1);
          float n1 = ftanh(ui + b2 + r1*(vh + b3));
          float hn = n1 + z1*(hOwn - n1);
          hOwn = hn;
          h1l[g*32 + h] = hn;
          *(float4*)&hv[0]  = *(const float4*)&h1l[g*32 + ko+0];
          *(float4*)&hv[4]  = *(const float4*)&h1l[g*32 + ko+4];
          *(float4*)&hv[8]  = *(const float4*)&h1l[g*32 + ko+8];
          *(float4*)&hv[12] = *(const float4*)&h1l[g*32 + ko+12];
          if (q == 0) acc[(b*256 + t)*64 + g*32 + h] = yown + hn;
        }
      }
    }
  } else {
    const int g = lane >> 5, qh = (lane >> 4) & 1, h = lane & 15, ko = qh*8;
    const int b = (blockIdx.x - 256)*4 + wid;
    float* gib  = smem + wid*3072;
    float* harr = smem + 12288 + wid*32;
    float ah[3][8];
    #pragma unroll
    for (int gt = 0; gt < 3; ++gt){
      const float* wp = whhH + (g*48 + gt*16 + h)*16 + ko;
      #pragma unroll
      for (int k = 0; k < 8; ++k) ah[gt][k] = wp[k];
    }
    #pragma unroll
    for (int gt = 0; gt < 3; ++gt){
      #pragma unroll
      for (int k = 0; k < 8; ++k) KEEP(ah[gt][k]);
    }
    const float bhr = bhhH[g*48+h], bhz = bhhH[g*48+16+h], bhn = bhhH[g*48+32+h];
    const float* gsrc = giH + b*24576;
    #pragma unroll
    for (int c0 = 0; c0 < 2; ++c0)
      for (int it = 0; it < 6; ++it)
        gload16(gsrc + c0*1536 + it*256 + lane*4, &gib[c0*1536 + it*256]);
    asm volatile("s_waitcnt vmcnt(0)" ::: "memory");

    float hv[8];
    #pragma unroll
    for (int k = 0; k < 8; ++k) hv[k] = 0.f;
    float hOwn = 0.f;
    float c_r = 0.f, c_z = 0.f, c_n = 0.f, p_r = 0.f, p_z = 0.f, p_n = 0.f;

    for (int t = 0; t < Tn; ++t){
      if ((t & 15) == 0){
        if (t){
          int c = t >> 4;
          if (c < 15){
            const float* gs = gsrc + (c+1)*1536;
            for (int it = 0; it < 6; ++it)
              gload16(gs + it*256 + lane*4, &gib[((c+1)&1)*1536 + it*256]);
            asm volatile("s_waitcnt vmcnt(6)" ::: "memory");
          } else {
            asm volatile("s_waitcnt vmcnt(0)" ::: "memory");
          }
        }
        const float* gt = &gib[((t>>4)&1)*1536 + (t&15)*96 + g*48];
        c_r = gt[h]; c_z = gt[16+h]; c_n = gt[32+h];
      } else { c_r = p_r; c_z = p_z; c_n = p_n; }
      if ((t+1) & 15){
        const float* gn = &gib[(((t+1)>>4)&1)*1536 + ((t+1)&15)*96 + g*48];
        p_r = gn[h]; p_z = gn[16+h]; p_n = gn[32+h];
      }
      float pr, pz, pn;
      DOT8(pr, hv, ah[0]); DOT8(pz, hv, ah[1]); DOT8(pn, hv, ah[2]);
      pr += __shfl_xor(pr,16); pz += __shfl_xor(pz,16); pn += __shfl_xor(pn,16);
      float r = fsig(c_r + pr + bhr);
      float z = fsig(c_z + pz + bhz);
      float nn = ftanh(c_n + r*(pn + bhn));
      float hn = nn + z*(hOwn - nn);
      hOwn = hn;
      harr[g*16 + h] = hn;
      *(float4*)&hv[0] = *(const float4*)&harr[g*16 + ko + 0];
      *(float4*)&hv[4] = *(const float4*)&harr[g*16 + ko + 4];
      if (qh == 0) dfh[(b*256 + t)*32 + g*16 + h] = hn;
    }
  }
}

// ---------- k7: float4-vectorized epilogue. Thread (fq 0..31, tq 0..7):
// 4 f per band, 4 consecutive t. Transposed LDS staging for vector reads.
__global__ __launch_bounds__(256) void k7(const float* __restrict__ acc,
    const float* __restrict__ dfh, const float* __restrict__ bmA,
    const float* __restrict__ wlo, const float* __restrict__ whi,
    const float* __restrict__ spec, float* __restrict__ out)
{
  __shared__ float accsT[64*36];
  __shared__ float dfhsT[32*36];
  __shared__ float bmtT[32*36];
  __shared__ float frcs[257];
  __shared__ int   ibds[257];
  const int tid = threadIdx.x;
  const int b  = blockIdx.x >> 3;
  const int t0 = (blockIdx.x & 7) * 32;
  for (int idx = tid; idx < 512; idx += 256){
    int tl = idx >> 4, c4 = (idx & 15)*4;
    float4 v = *(const float4*)&acc[(b*256 + t0 + tl)*64 + c4];
    accsT[(c4+0)*36 + tl] = v.x; accsT[(c4+1)*36 + tl] = v.y;
    accsT[(c4+2)*36 + tl] = v.z; accsT[(c4+3)*36 + tl] = v.w;
  }
  {
    int tl = tid >> 3, c4 = (tid & 7)*4;
    float4 v = *(const float4*)&dfh[(b*256 + t0 + tl)*32 + c4];
    dfhsT[(c4+0)*36 + tl] = v.x; dfhsT[(c4+1)*36 + tl] = v.y;
    dfhsT[(c4+2)*36 + tl] = v.z; dfhsT[(c4+3)*36 + tl] = v.w;
    float4 u = *(const float4*)&bmA[(b*Tn + t0 + tl)*32 + c4];
    bmtT[(c4+0)*36 + tl] = u.x; bmtT[(c4+1)*36 + tl] = u.y;
    bmtT[(c4+2)*36 + tl] = u.z; bmtT[(c4+3)*36 + tl] = u.w;
  }
  for (int f = tid; f < 257; f += 256){
    int i = 0;
    #pragma unroll
    for (int k = 1; k < 31; ++k) if (f >= EB[k]) i = k;
    ibds[f] = i;
    frcs[f] = (f < 256) ? (float)(f - EB[i]) / (float)(EB[i+1] - EB[i]) : 0.f;
  }
  __syncthreads();
  const int fq = tid >> 3, tq = tid & 7;
  float* out1 = out + 16842752;
  float* out2 = out + 2*16842752;
  float* out3 = out + 3*16842752;

  // ---- low band: f = fq*4 + jf
  {
    float4 p[4];
    #pragma unroll
    for (int jf = 0; jf < 4; ++jf) p[jf] = make_float4(0.f,0.f,0.f,0.f);
    for (int i = 0; i < 64; ++i){
      float4 av = *(const float4*)&accsT[i*36 + tq*4];
      float4 wv = *(const float4*)&wlo[i*128 + fq*4];
      FMA4V(p[0], av, wv.x); FMA4V(p[1], av, wv.y);
      FMA4V(p[2], av, wv.z); FMA4V(p[3], av, wv.w);
    }
    #pragma unroll
    for (int jf = 0; jf < 4; ++jf){
      int f = fq*4 + jf;
      int i = ibds[f]; float fr = frcs[f];
      float4 b0v = *(const float4*)&bmtT[i*36 + tq*4];
      float4 b1v = *(const float4*)&bmtT[(i+1)*36 + tq*4];
      float4 full;
      full.x = b0v.x*(1.f-fr) + b1v.x*fr; full.y = b0v.y*(1.f-fr) + b1v.y*fr;
      full.z = b0v.z*(1.f-fr) + b1v.z*fr; full.w = b0v.w*(1.f-fr) + b1v.w*fr;
      float4 m;
      m.x = fsig(p[jf].x)*full.x; m.y = fsig(p[jf].y)*full.y;
      m.z = fsig(p[jf].z)*full.z; m.w = fsig(p[jf].w)*full.w;
      int base = (b*257 + f)*Tn + t0 + tq*4;
      float4 s01 = *(const float4*)&spec[base*2];
      float4 s23 = *(const float4*)&spec[base*2 + 4];
      float fm0 = full.x*m.x, fm1 = full.y*m.y, fm2 = full.z*m.z, fm3 = full.w*m.w;
      float sx0 = s01.x*fm0, sy0 = s01.y*fm0;
      float sx1 = s01.z*fm1, sy1 = s01.w*fm1;
      float sx2 = s23.x*fm2, sy2 = s23.y*fm2;
      float sx3 = s23.z*fm3, sy3 = s23.w*fm3;
      *(float4*)&out[base]  = full;
      *(float4*)&out1[base] = m;
      float4 mag;
      mag.x = sqrtf(sx0*sx0 + sy0*sy0); mag.y = sqrtf(sx1*sx1 + sy1*sy1);
      mag.z = sqrtf(sx2*sx2 + sy2*sy2); mag.w = sqrtf(sx3*sx3 + sy3*sy3);
      *(float4*)&out2[base] = mag;
      *(float4*)&out3[base*2]     = make_float4(sx0, sy0, sx1, sy1);
      *(float4*)&out3[base*2 + 4] = make_float4(sx2, sy2, sx3, sy3);
    }
  }
  // ---- high band: f = 128 + fq*4 + jf; g = fq>>4; col = (fq&15)*4
  {
    const int g = fq >> 4;
    const int col = (fq & 15)*4;
    float4 p[4];
    #pragma unroll
    for (int jf = 0; jf < 4; ++jf) p[jf] = make_float4(0.f,0.f,0.f,0.f);
    for (int i = 0; i < 16; ++i){
      float4 dv = *(const float4*)&dfhsT[(g*16 + i)*36 + tq*4];
      float4 wv = *(const float4*)&whi[(g*16 + i)*64 + col];
      FMA4V(p[0], dv, wv.x); FMA4V(p[1], dv, wv.y);
      FMA4V(p[2], dv, wv.z); FMA4V(p[3], dv, wv.w);
    }
    #pragma unroll
    for (int jf = 0; jf < 4; ++jf){
      int f = 128 + fq*4 + jf;
      int i = ibds[f]; float fr = frcs[f];
      float4 b0v = *(const float4*)&bmtT[i*36 + tq*4];
      float4 b1v = *(const float4*)&bmtT[(i+1)*36 + tq*4];
      float4 full;
      full.x = b0v.x*(1.f-fr) + b1v.x*fr; full.y = b0v.y*(1.f-fr) + b1v.y*fr;
      full.z = b0v.z*(1.f-fr) + b1v.z*fr; full.w = b0v.w*(1.f-fr) + b1v.w*fr;
      float4 m;
      m.x = fsig(p[jf].x)*full.x; m.y = fsig(p[jf].y)*full.y;
      m.z = fsig(p[jf].z)*full.z; m.w = fsig(p[jf].w)*full.w;
      int base = (b*257 + f)*Tn + t0 + tq*4;
      float4 s01 = *(const float4*)&spec[base*2];
      float4 s23 = *(const float4*)&spec[base*2 + 4];
      float fm0 = full.x*m.x, fm1 = full.y*m.y, fm2 = full.z*m.z, fm3 = full.w*m.w;
      float sx0 = s01.x*fm0, sy0 = s01.y*fm0;
      float sx1 = s01.z*fm1, sy1 = s01.w*fm1;
      float sx2 = s23.x*fm2, sy2 = s23.y*fm2;
      float sx3 = s23.z*fm3, sy3 = s23.w*fm3;
      *(float4*)&out[base]  = full;
      *(float4*)&out1[base] = m;
      float4 mag;
      mag.x = sqrtf(sx0*sx0 + sy0*sy0); mag.y = sqrtf(sx1*sx1 + sy1*sy1);
      mag.z = sqrtf(sx2*sx2 + sy2*sy2); mag.w = sqrtf(sx3*sx3 + sy3*sy3);
      *(float4*)&out2[base] = mag;
      *(float4*)&out3[base*2]     = make_float4(sx0, sy0, sx1, sy1);
      *(float4*)&out3[base*2 + 4] = make_float4(sx2, sy2, sx3, sy3);
    }
  }
  // ---- f = 256: zeros
  if (tid < 8){
    int base = (b*257 + 256)*Tn + t0 + tid*4;
    float4 z = make_float4(0.f,0.f,0.f,0.f);
    *(float4*)&out[base]  = z;
    *(float4*)&out1[base] = z;
    *(float4*)&out2[base] = z;
    *(float4*)&out3[base*2]     = z;
    *(float4*)&out3[base*2 + 4] = z;
  }
}

extern "C" void kernel_launch(void* const* d_in, const int* in_sizes, int n_in,
                              void* d_out, int out_size, void* d_ws, size_t ws_size,
                              hipStream_t stream){
  const float* mi   = (const float*)d_in[0];
  const float* spec = (const float*)d_in[1];
  const float* lpi  = (const float*)d_in[2];
  const float* s1w  = (const float*)d_in[5];
  const float* s1b  = (const float*)d_in[6];
  const float* wih0 = (const float*)d_in[7];
  const float* whh0 = (const float*)d_in[8];
  const float* bih0 = (const float*)d_in[9];
  const float* bhh0 = (const float*)d_in[10];
  const float* wih1 = (const float*)d_in[11];
  const float* whh1 = (const float*)d_in[12];
  const float* bih1 = (const float*)d_in[13];
  const float* bhh1 = (const float*)d_in[14];
  const float* fco  = (const float*)d_in[15];
  const float* filw = (const float*)d_in[16];
  const float* plo  = (const float*)d_in[17];
  const float* fihw = (const float*)d_in[18];
  const float* phi  = (const float*)d_in[19];
  const float* glw_ih = (const float*)d_in[20];
  const float* glw_hh = (const float*)d_in[21];
  const float* glb_ih = (const float*)d_in[22];
  const float* glb_hh = (const float*)d_in[23];
  const float* ghw_ih = (const float*)d_in[24];
  const float* ghw_hh = (const float*)d_in[25];
  const float* ghb_ih = (const float*)d_in[26];
  const float* ghb_hh = (const float*)d_in[27];
  const float* folw = (const float*)d_in[28];
  const float* fohw = (const float*)d_in[29];

  // big gi scratch lives in d_out (fully overwritten by k7 at the end)
  float* outf = (float*)d_out;
  float* giL  = outf;                     // [b][t][192] 12,582,912
  float* gi0  = outf + 12582912;          // [b][t][96]   6,291,456
  float* giH  = outf + 18874368;          // [b][t][96]   6,291,456

  float* ws   = (float*)d_ws;
  float* wcT  = ws;                       // 6144
  float* bc   = ws + 6144;                // 96
  float* wBT  = ws + 6240;                // 7680
  float* bB   = ws + 13920;               // 288
  float* bmA  = ws + 14336;               // [b][t][32]  2,097,152
  float* acc  = ws + 2111488;             // [b][t][64]  4,194,304
  float* dfh  = ws + 6305792;             // [b][t][32]  2,097,152
  float* pmid = ws + 8402944;             // [b][t][96]  6,291,456
  float* out  = (float*)d_out;

  k0<<<56, 256, 0, stream>>>(s1w, s1b, wih0, bih0, glw_ih, glb_ih, ghw_ih, ghb_ih,
                             wcT, bc, wBT, bB);
  k1<<<2048, 256, 0, stream>>>(mi, wcT, bc, gi0);
  kSP<<<2304, 128, 0, stream>>>(gi0, whh0, bhh0, wih1, whh1, bih1, bhh1, fco, bmA,
                                lpi, filw, fihw, pmid);
  kPb<<<2048, 256, 0, stream>>>(bmA, pmid, filw, plo, fihw, phi, wBT, bB, giL, giH);
  kR2<<<320, 256, 0, stream>>>(giL, giH, glw_ih, glw_hh, glb_ih, glb_hh,
                               ghw_hh, ghb_hh, acc, dfh);
  k7<<<2048, 256, 0, stream>>>(acc, dfh, bmA, folw, fohw, spec, out);
}